// Round 2
// baseline (643.895 us; speedup 1.0000x reference)
//
#include <hip/hip_runtime.h>
#include <hip/hip_bf16.h>

#define DIN 128
#define HID1 128
#define HID2 64
#define OUTD 40

__device__ __forceinline__ float bf2f(unsigned short u) {
    union { unsigned int i; float f; } c;
    c.i = ((unsigned int)u) << 16;
    return c.f;
}
__device__ __forceinline__ unsigned short f2bf(float f) {
    union { float f; unsigned int i; } c; c.f = f;
    unsigned int r = c.i + 0x7FFFu + ((c.i >> 16) & 1u);   // RNE
    return (unsigned short)(r >> 16);
}

// ---------------- runtime dtype detection ----------------
// flags[0] = 1 if float tensors are f32, 0 if bf16
// flags[1] = 1 if edge_index is int64, 0 if int32
__global__ void detect_kernel(const unsigned short* __restrict__ xu,
                              const int* __restrict__ ei, int* __restrict__ flags) {
    __shared__ int sh[2];
    if (threadIdx.x < 2) sh[threadIdx.x] = 0;
    __syncthreads();
    int bad = 0;
    for (int i = threadIdx.x; i < 2048; i += 256) {
        // even u16s: if x is f32 these are low mantissa halves -> implausible bf16s
        float v = bf2f(xu[2 * i]);
        float a = fabsf(v);
        if (!(a <= 1e4f) || (v != 0.f && a < 1e-4f)) bad++;   // NaN fails a<=1e4
    }
    int zodd = 0;
    for (int i = threadIdx.x; i < 1024; i += 256)
        if (ei[2 * i + 1] == 0) zodd++;   // int64 -> hi words all zero
    atomicAdd(&sh[0], bad);
    atomicAdd(&sh[1], zodd);
    __syncthreads();
    if (threadIdx.x == 0) {
        flags[0] = (sh[0] > 512) ? 1 : 0;
        flags[1] = (sh[1] > 512) ? 1 : 0;
    }
}

__device__ __forceinline__ int get_src(const int* ei, int E, int e, int e64) {
    return e64 ? ei[2 * e] : ei[e];
}
__device__ __forceinline__ int get_dst(const int* ei, int E, int e, int e64) {
    return e64 ? ei[2 * (E + e)] : ei[E + e];
}

// ---------------- graph preprocessing ----------------

__global__ void init_cnt_kernel(int* __restrict__ cnt, int N) {
    int i = blockIdx.x * blockDim.x + threadIdx.x;
    if (i < N) cnt[i] = 0;
}

__global__ void hist_kernel(const int* __restrict__ ei, int* __restrict__ cnt,
                            int E, int N, const int* __restrict__ flags) {
    int e64 = flags[1];
    int e = blockIdx.x * blockDim.x + threadIdx.x;
    if (e < E) {
        int d = get_dst(ei, E, e, e64);
        if ((unsigned)d < (unsigned)N) atomicAdd(&cnt[d], 1);
    }
}

__global__ void dinv_kernel(const int* __restrict__ cnt, float* __restrict__ dinv, int N) {
    int i = blockIdx.x * blockDim.x + threadIdx.x;
    if (i < N) dinv[i] = 1.0f / sqrtf((float)(cnt[i] + 1));   // +1 self loop
}

__launch_bounds__(1024)
__global__ void scan_kernel(const int* __restrict__ cnt, int* __restrict__ indptr,
                            int* __restrict__ cursor, int N) {
    __shared__ int part[1024];
    int t = threadIdx.x;
    int CH = (N + 1023) / 1024;
    int lo = t * CH, hi = lo + CH; if (hi > N) hi = N;
    int s = 0;
    for (int i = lo; i < hi; ++i) s += cnt[i];
    part[t] = s;
    __syncthreads();
    for (int off = 1; off < 1024; off <<= 1) {
        int v = (t >= off) ? part[t - off] : 0;
        __syncthreads();
        part[t] += v;
        __syncthreads();
    }
    int run = (t > 0) ? part[t - 1] : 0;
    for (int i = lo; i < hi; ++i) {
        indptr[i] = run; cursor[i] = run;
        run += cnt[i];
    }
    if (t == 0) indptr[N] = part[1023];
}

__global__ void fill_kernel(const int* __restrict__ ei, int* __restrict__ cursor,
                            int* __restrict__ csr_src, int E, int N,
                            const int* __restrict__ flags) {
    int e64 = flags[1];
    int e = blockIdx.x * blockDim.x + threadIdx.x;
    if (e < E) {
        int d = get_dst(ei, E, e, e64);
        if ((unsigned)d < (unsigned)N) {
            int s = get_src(ei, E, e, e64);
            if ((unsigned)s >= (unsigned)N) s = 0;
            int p = atomicAdd(&cursor[d], 1);
            csr_src[p] = s;
        }
    }
}

// ---------------- weight conversion into f32 / bf16 arenas ----------------

struct WCvt {
    const void* p[14];
    int sz[14];
    int off[14];
    int tobf[14];
};

__global__ void wcvt_kernel(WCvt w, unsigned short* __restrict__ wbf,
                            float* __restrict__ wf, const int* __restrict__ flags) {
    int xf32 = flags[0];
    int stride = gridDim.x * blockDim.x;
    int tid = blockIdx.x * blockDim.x + threadIdx.x;
    for (int a = 0; a < 14; ++a) {
        const float* pf = (const float*)w.p[a];
        const unsigned short* pb = (const unsigned short*)w.p[a];
        int n = w.sz[a], off = w.off[a], tobf = w.tobf[a];
        for (int i = tid; i < n; i += stride) {
            float v = xf32 ? pf[i] : bf2f(pb[i]);
            if (tobf) wbf[off + i] = f2bf(v);   // bf16 in, bf16 out: exact round-trip
            else      wf[off + i]  = v;
        }
    }
}

// ---------------- dense matmul: C[N,M](bf16) = A[N,K] x W[K,M](bf16) ----------------

template<typename AT> __device__ __forceinline__ float toF(AT v);
template<> __device__ __forceinline__ float toF<float>(float v) { return v; }
template<> __device__ __forceinline__ float toF<unsigned short>(unsigned short v) { return bf2f(v); }

// mode: -1 = always run; 0 = run iff x is bf16; 1 = run iff x is f32
template<int K, int M, int RPB, typename AT>
__launch_bounds__(256)
__global__ void mm_kernel(const AT* __restrict__ A, const unsigned short* __restrict__ Wbf,
                          unsigned short* __restrict__ C, int N,
                          const int* __restrict__ flags, int mode) {
    if (mode >= 0 && flags[0] != mode) return;
    __shared__ float As[K][RPB + 16];
    __shared__ unsigned short Ws[K][M];
    int row0 = blockIdx.x * RPB;
    for (int idx = threadIdx.x; idx < RPB * K; idx += 256) {
        int r = idx / K, k = idx - r * K;   // coalesced over k
        int row = row0 + r;
        As[k][r] = (row < N) ? toF<AT>(A[(size_t)row * K + k]) : 0.f;
    }
    {
        const unsigned int* W32 = (const unsigned int*)Wbf;
        unsigned int* Ws32 = (unsigned int*)&Ws[0][0];
        for (int idx = threadIdx.x; idx < K * M / 2; idx += 256) Ws32[idx] = W32[idx];
    }
    __syncthreads();
    constexpr int CG = M / 4;
    int cg = threadIdx.x % CG;
    int rg = threadIdx.x / CG;
    int r = rg * 4, c = cg * 4;
    float acc[4][4] = {};
    #pragma unroll 4
    for (int k = 0; k < K; ++k) {
        float4 a = *(const float4*)&As[k][r];
        ushort4 wq = *(const ushort4*)&Ws[k][c];
        float w0 = bf2f(wq.x), w1 = bf2f(wq.y), w2 = bf2f(wq.z), w3 = bf2f(wq.w);
        acc[0][0] += a.x * w0; acc[0][1] += a.x * w1; acc[0][2] += a.x * w2; acc[0][3] += a.x * w3;
        acc[1][0] += a.y * w0; acc[1][1] += a.y * w1; acc[1][2] += a.y * w2; acc[1][3] += a.y * w3;
        acc[2][0] += a.z * w0; acc[2][1] += a.z * w1; acc[2][2] += a.z * w2; acc[2][3] += a.z * w3;
        acc[3][0] += a.w * w0; acc[3][1] += a.w * w1; acc[3][2] += a.w * w2; acc[3][3] += a.w * w3;
    }
    #pragma unroll
    for (int i = 0; i < 4; ++i) {
        int row = row0 + r + i;
        if (row < N) {
            ushort4 v;
            v.x = f2bf(acc[i][0]); v.y = f2bf(acc[i][1]);
            v.z = f2bf(acc[i][2]); v.w = f2bf(acc[i][3]);
            *(ushort4*)&C[(size_t)row * M + c] = v;
        }
    }
}

// ---------------- aggregation + optional ReLU/LN; one wave per node ----------------
// out[i] = sum_{e: dst=i} h[src_e]*dinv[src_e]*dinv[i] + h[i]*dinv[i]^2 + b

template<int H, bool RELU_LN, bool EMB>
__launch_bounds__(256)
__global__ void agg_kernel(const unsigned short* __restrict__ h,
                           const int* __restrict__ indptr,
                           const int* __restrict__ csr_src,
                           const float* __restrict__ dinv,
                           const float* __restrict__ bias,
                           const float* __restrict__ gamma,
                           const float* __restrict__ beta,
                           unsigned short* __restrict__ out,
                           void* __restrict__ out_emb,
                           int N, const int* __restrict__ flags) {
    constexpr int VPL = H / 64;
    int lane = threadIdx.x & 63;
    int node = blockIdx.x * (blockDim.x >> 6) + (threadIdx.x >> 6);
    if (node >= N) return;
    float di = dinv[node];
    int c0 = lane * VPL;
    const unsigned short* hrow = h + (size_t)node * H + c0;
    float acc[VPL];
    if constexpr (VPL == 2) {
        unsigned int u = *(const unsigned int*)hrow;
        acc[0] = bf2f((unsigned short)(u & 0xffff)) * (di * di);
        acc[1] = bf2f((unsigned short)(u >> 16)) * (di * di);
    } else {
        acc[0] = bf2f(hrow[0]) * (di * di);
    }
    int beg = indptr[node], end = indptr[node + 1];
    for (int base = beg; base < end; base += 64) {
        int m = end - base; if (m > 64) m = 64;
        int s = 0; float dn = 0.f;
        if (lane < m) {
            s = csr_src[base + lane];
            if ((unsigned)s >= (unsigned)N) s = 0;
            dn = dinv[s];
        }
        int j = 0;
        for (; j + 2 <= m; j += 2) {
            int s0 = __shfl(s, j, 64), s1 = __shfl(s, j + 1, 64);
            float n0 = __shfl(dn, j, 64) * di, n1 = __shfl(dn, j + 1, 64) * di;
            const unsigned short* r0 = h + (size_t)s0 * H + c0;
            const unsigned short* r1 = h + (size_t)s1 * H + c0;
            if constexpr (VPL == 2) {
                unsigned int u0 = *(const unsigned int*)r0;
                unsigned int u1 = *(const unsigned int*)r1;
                acc[0] += bf2f((unsigned short)(u0 & 0xffff)) * n0
                        + bf2f((unsigned short)(u1 & 0xffff)) * n1;
                acc[1] += bf2f((unsigned short)(u0 >> 16)) * n0
                        + bf2f((unsigned short)(u1 >> 16)) * n1;
            } else {
                acc[0] += bf2f(r0[0]) * n0 + bf2f(r1[0]) * n1;
            }
        }
        if (j < m) {
            int s0 = __shfl(s, j, 64);
            float n0 = __shfl(dn, j, 64) * di;
            const unsigned short* r0 = h + (size_t)s0 * H + c0;
            if constexpr (VPL == 2) {
                unsigned int u0 = *(const unsigned int*)r0;
                acc[0] += bf2f((unsigned short)(u0 & 0xffff)) * n0;
                acc[1] += bf2f((unsigned short)(u0 >> 16)) * n0;
            } else {
                acc[0] += bf2f(r0[0]) * n0;
            }
        }
    }
    #pragma unroll
    for (int v = 0; v < VPL; ++v) acc[v] += bias[c0 + v];
    if constexpr (RELU_LN) {
        #pragma unroll
        for (int v = 0; v < VPL; ++v) acc[v] = fmaxf(acc[v], 0.f);
        float s = 0.f, sq = 0.f;
        #pragma unroll
        for (int v = 0; v < VPL; ++v) { s += acc[v]; sq += acc[v] * acc[v]; }
        #pragma unroll
        for (int off = 32; off >= 1; off >>= 1) {
            s += __shfl_xor(s, off, 64);
            sq += __shfl_xor(sq, off, 64);
        }
        float mu = s * (1.0f / H);
        float var = fmaxf(sq * (1.0f / H) - mu * mu, 0.f);
        float inv = 1.0f / sqrtf(var + 1e-5f);
        #pragma unroll
        for (int v = 0; v < VPL; ++v)
            acc[v] = (acc[v] - mu) * inv * gamma[c0 + v] + beta[c0 + v];
    }
    #pragma unroll
    for (int v = 0; v < VPL; ++v) out[(size_t)node * H + c0 + v] = f2bf(acc[v]);
    if constexpr (EMB) {
        if (flags[0]) {
            float* o = (float*)out_emb;
            #pragma unroll
            for (int v = 0; v < VPL; ++v) o[(size_t)node * H + c0 + v] = acc[v];
        } else {
            unsigned short* o = (unsigned short*)out_emb;
            #pragma unroll
            for (int v = 0; v < VPL; ++v) o[(size_t)node * H + c0 + v] = f2bf(acc[v]);
        }
    }
}

// ---------------- post-mp head + log_softmax; one wave per node ----------------

__launch_bounds__(256)
__global__ void head_kernel(const unsigned short* __restrict__ emb,
                            const float* __restrict__ Wp1,
                            const float* __restrict__ bp1,
                            const float* __restrict__ Wp2,
                            const float* __restrict__ bp2,
                            void* __restrict__ d_out, int N,
                            const int* __restrict__ flags) {
    __shared__ float W1s[64 * 64];
    __shared__ float W2s[64 * OUTD];
    __shared__ float b1s[64];
    __shared__ float b2s[OUTD];
    for (int idx = threadIdx.x; idx < 64 * 64; idx += 256) W1s[idx] = Wp1[idx];
    for (int idx = threadIdx.x; idx < 64 * OUTD; idx += 256) W2s[idx] = Wp2[idx];
    if (threadIdx.x < 64) b1s[threadIdx.x] = bp1[threadIdx.x];
    if (threadIdx.x < OUTD) b2s[threadIdx.x] = bp2[threadIdx.x];
    __syncthreads();
    int lane = threadIdx.x & 63;
    int node = blockIdx.x * 4 + (threadIdx.x >> 6);
    if (node >= N) return;
    int xf32 = flags[0];
    float r = fmaxf(bf2f(emb[(size_t)node * 64 + lane]), 0.f);
    float t = b1s[lane];
    #pragma unroll 8
    for (int k = 0; k < 64; ++k) t += __shfl(r, k, 64) * W1s[k * 64 + lane];
    float u = (lane < OUTD) ? b2s[lane] : -INFINITY;
    #pragma unroll 8
    for (int k = 0; k < 64; ++k) {
        float tk = __shfl(t, k, 64);
        if (lane < OUTD) u += tk * W2s[k * OUTD + lane];
    }
    float mx = u;
    #pragma unroll
    for (int off = 32; off >= 1; off >>= 1) mx = fmaxf(mx, __shfl_xor(mx, off, 64));
    float ex = (lane < OUTD) ? __expf(u - mx) : 0.f;
    float sum = ex;
    #pragma unroll
    for (int off = 32; off >= 1; off >>= 1) sum += __shfl_xor(sum, off, 64);
    float res = u - mx - __logf(sum);
    if (lane < OUTD) {
        char* base = (char*)d_out + (size_t)N * HID2 * (xf32 ? 4 : 2);
        if (xf32) ((float*)base)[(size_t)node * OUTD + lane] = res;
        else ((unsigned short*)base)[(size_t)node * OUTD + lane] = f2bf(res);
    }
}

// ---------------- launch ----------------

extern "C" void kernel_launch(void* const* d_in, const int* in_sizes, int n_in,
                              void* d_out, int out_size, void* d_ws, size_t ws_size,
                              hipStream_t stream) {
    const unsigned short* xu = (const unsigned short*)d_in[0];
    const float*          xf = (const float*)d_in[0];
    const int*            ei = (const int*)d_in[1];

    const int N = in_sizes[0] / DIN;   // 50000
    const int E = in_sizes[1] / 2;     // 800000

    // workspace layout (256B aligned slices), total ~30 MB
    size_t off = 0;
    auto take = [&](size_t bytes) {
        size_t cur = off;
        off += (bytes + 255) & ~(size_t)255;
        return cur;
    };
    char* ws = (char*)d_ws;
    int*   flags   = (int*)  (ws + take(256));
    int*   cnt     = (int*)  (ws + take((size_t)N * 4));
    float* dinv    = (float*)(ws + take((size_t)N * 4));
    int*   indptr  = (int*)  (ws + take((size_t)(N + 1) * 4));
    int*   cursor  = (int*)  (ws + take((size_t)N * 4));
    int*   csr_src = (int*)  (ws + take((size_t)E * 4));
    unsigned short* wbf = (unsigned short*)(ws + take(32768 * 2));
    float*          wf  = (float*)         (ws + take(8192 * 4));
    unsigned short* hbuf = (unsigned short*)(ws + take((size_t)N * DIN * 2));
    unsigned short* abuf = (unsigned short*)(ws + take((size_t)N * DIN * 2));
    (void)ws_size; (void)n_in; (void)out_size;

    const int TB = 256;
    dim3 blk(TB);

    // dtype detection
    detect_kernel<<<dim3(1), blk, 0, stream>>>(xu, ei, flags);

    // graph preprocessing
    init_cnt_kernel<<<dim3((N + TB - 1) / TB), blk, 0, stream>>>(cnt, N);
    hist_kernel<<<dim3((E + TB - 1) / TB), blk, 0, stream>>>(ei, cnt, E, N, flags);
    dinv_kernel<<<dim3((N + TB - 1) / TB), blk, 0, stream>>>(cnt, dinv, N);
    scan_kernel<<<dim3(1), dim3(1024), 0, stream>>>(cnt, indptr, cursor, N);
    fill_kernel<<<dim3((E + TB - 1) / TB), blk, 0, stream>>>(ei, cursor, csr_src, E, N, flags);

    // weight conversion: W1/W2/W3 -> bf16 arena; everything else -> f32 arena
    WCvt w;
    int bfoff = 0, foff = 0;
    int offs[14];
    for (int a = 0; a < 14; ++a) {
        int idx = a + 2;
        w.p[a] = d_in[idx];
        w.sz[a] = in_sizes[idx];
        int tobf = (idx == 2 || idx == 4 || idx == 6) ? 1 : 0;
        w.tobf[a] = tobf;
        if (tobf) { w.off[a] = bfoff; bfoff += in_sizes[idx]; }
        else      { w.off[a] = foff;  foff  += in_sizes[idx]; }
        offs[a] = w.off[a];
    }
    wcvt_kernel<<<dim3(64), blk, 0, stream>>>(w, wbf, wf, flags);

    unsigned short* W1b = wbf + offs[0];
    unsigned short* W2b = wbf + offs[2];
    unsigned short* W3b = wbf + offs[4];
    float* b1f  = wf + offs[1];
    float* b2f  = wf + offs[3];
    float* b3f  = wf + offs[5];
    float* g1f  = wf + offs[6];
    float* be1f = wf + offs[7];
    float* g2f  = wf + offs[8];
    float* be2f = wf + offs[9];
    float* Wp1f = wf + offs[10];
    float* bp1f = wf + offs[11];
    float* Wp2f = wf + offs[12];
    float* bp2f = wf + offs[13];

    // layer 1 (dual-dtype x; exactly one variant runs)
    mm_kernel<DIN, HID1, 32, unsigned short><<<dim3((N + 31) / 32), blk, 0, stream>>>(
        xu, W1b, hbuf, N, flags, 0);
    mm_kernel<DIN, HID1, 32, float><<<dim3((N + 31) / 32), blk, 0, stream>>>(
        xf, W1b, hbuf, N, flags, 1);
    agg_kernel<HID1, true, false><<<dim3((N + 3) / 4), blk, 0, stream>>>(
        hbuf, indptr, csr_src, dinv, b1f, g1f, be1f, abuf, nullptr, N, flags);

    // layer 2
    mm_kernel<HID1, HID2, 64, unsigned short><<<dim3((N + 63) / 64), blk, 0, stream>>>(
        abuf, W2b, hbuf, N, flags, -1);
    agg_kernel<HID2, true, false><<<dim3((N + 3) / 4), blk, 0, stream>>>(
        hbuf, indptr, csr_src, dinv, b2f, g2f, be2f, abuf, nullptr, N, flags);

    // layer 3 -> emb (bf16 copy in abuf for head; d_out per detected dtype)
    mm_kernel<HID2, HID2, 64, unsigned short><<<dim3((N + 63) / 64), blk, 0, stream>>>(
        abuf, W3b, hbuf, N, flags, -1);
    agg_kernel<HID2, false, true><<<dim3((N + 3) / 4), blk, 0, stream>>>(
        hbuf, indptr, csr_src, dinv, b3f, nullptr, nullptr, abuf, d_out, N, flags);

    // head: MLP + log_softmax
    head_kernel<<<dim3((N + 3) / 4), blk, 0, stream>>>(
        abuf, Wp1f, bp1f, Wp2f, bp2f, d_out, N, flags);
}

// Round 3
// 569.794 us; speedup vs baseline: 1.1300x; 1.1300x over previous
//
#include <hip/hip_runtime.h>
#include <hip/hip_bf16.h>

#define DIN 128
#define HID1 128
#define HID2 64
#define OUTD 40

__device__ __forceinline__ float bf2f(unsigned short u) {
    union { unsigned int i; float f; } c;
    c.i = ((unsigned int)u) << 16;
    return c.f;
}
__device__ __forceinline__ unsigned short f2bf(float f) {
    union { float f; unsigned int i; } c; c.f = f;
    unsigned int r = c.i + 0x7FFFu + ((c.i >> 16) & 1u);   // RNE
    return (unsigned short)(r >> 16);
}
__device__ __forceinline__ unsigned int packbf(float lo, float hi) {
    return (unsigned int)f2bf(lo) | ((unsigned int)f2bf(hi) << 16);
}

// ---------------- runtime dtype detection ----------------
// flags[0] = 1 if float tensors are f32, 0 if bf16
// flags[1] = 1 if edge_index is int64, 0 if int32
__global__ void detect_kernel(const unsigned short* __restrict__ xu,
                              const int* __restrict__ ei, int* __restrict__ flags) {
    __shared__ int sh[2];
    if (threadIdx.x < 2) sh[threadIdx.x] = 0;
    __syncthreads();
    int bad = 0;
    for (int i = threadIdx.x; i < 2048; i += 256) {
        float v = bf2f(xu[2 * i]);
        float a = fabsf(v);
        if (!(a <= 1e4f) || (v != 0.f && a < 1e-4f)) bad++;
    }
    int zodd = 0;
    for (int i = threadIdx.x; i < 1024; i += 256)
        if (ei[2 * i + 1] == 0) zodd++;
    atomicAdd(&sh[0], bad);
    atomicAdd(&sh[1], zodd);
    __syncthreads();
    if (threadIdx.x == 0) {
        flags[0] = (sh[0] > 512) ? 1 : 0;
        flags[1] = (sh[1] > 512) ? 1 : 0;
    }
}

__device__ __forceinline__ int get_src(const int* ei, int E, int e, int e64) {
    return e64 ? ei[2 * e] : ei[e];
}
__device__ __forceinline__ int get_dst(const int* ei, int E, int e, int e64) {
    return e64 ? ei[2 * (E + e)] : ei[E + e];
}

// ---------------- graph preprocessing ----------------

__global__ void init_cnt_kernel(int* __restrict__ cnt, int N) {
    int i = blockIdx.x * blockDim.x + threadIdx.x;
    if (i < N) cnt[i] = 0;
}

__global__ void hist_kernel(const int* __restrict__ ei, int* __restrict__ cnt,
                            int E, int N, const int* __restrict__ flags) {
    int e64 = flags[1];
    int e = blockIdx.x * blockDim.x + threadIdx.x;
    if (e < E) {
        int d = get_dst(ei, E, e, e64);
        if ((unsigned)d < (unsigned)N) atomicAdd(&cnt[d], 1);
    }
}

__launch_bounds__(1024)
__global__ void scan_kernel(const int* __restrict__ cnt, int* __restrict__ indptr,
                            int* __restrict__ cursor, float* __restrict__ dinv, int N) {
    __shared__ int part[1024];
    int t = threadIdx.x;
    int CH = (N + 1023) / 1024;
    int lo = t * CH, hi = lo + CH; if (hi > N) hi = N;
    int s = 0;
    for (int i = lo; i < hi; ++i) s += cnt[i];
    part[t] = s;
    __syncthreads();
    for (int off = 1; off < 1024; off <<= 1) {
        int v = (t >= off) ? part[t - off] : 0;
        __syncthreads();
        part[t] += v;
        __syncthreads();
    }
    int run = (t > 0) ? part[t - 1] : 0;
    for (int i = lo; i < hi; ++i) {
        int c = cnt[i];
        indptr[i] = run; cursor[i] = run;
        dinv[i] = 1.0f / sqrtf((float)(c + 1));   // +1 self loop
        run += c;
    }
    if (t == 0) indptr[N] = part[1023];
}

__global__ void fill_kernel(const int* __restrict__ ei, int* __restrict__ cursor,
                            int* __restrict__ csr_src, int E, int N,
                            const int* __restrict__ flags) {
    int e64 = flags[1];
    int e = blockIdx.x * blockDim.x + threadIdx.x;
    if (e < E) {
        int d = get_dst(ei, E, e, e64);
        if ((unsigned)d < (unsigned)N) {
            int s = get_src(ei, E, e, e64);
            if ((unsigned)s >= (unsigned)N) s = 0;
            int p = atomicAdd(&cursor[d], 1);
            csr_src[p] = s;
        }
    }
}

// ---------------- weight conversion into f32 / bf16 arenas ----------------

struct WCvt {
    const void* p[14];
    int sz[14];
    int off[14];
    int tobf[14];
};

__global__ void wcvt_kernel(WCvt w, unsigned short* __restrict__ wbf,
                            float* __restrict__ wf, const int* __restrict__ flags) {
    int xf32 = flags[0];
    int stride = gridDim.x * blockDim.x;
    int tid = blockIdx.x * blockDim.x + threadIdx.x;
    for (int a = 0; a < 14; ++a) {
        const float* pf = (const float*)w.p[a];
        const unsigned short* pb = (const unsigned short*)w.p[a];
        int n = w.sz[a], off = w.off[a], tobf = w.tobf[a];
        for (int i = tid; i < n; i += stride) {
            float v = xf32 ? pf[i] : bf2f(pb[i]);
            if (tobf) wbf[off + i] = f2bf(v);
            else      wf[off + i]  = v;
        }
    }
}

// ---------------- dense matmul: C[N,M](bf16) = A[N,K] x W[K,M](bf16) ----------------

template<typename AT> __device__ __forceinline__ float toF(AT v);
template<> __device__ __forceinline__ float toF<float>(float v) { return v; }
template<> __device__ __forceinline__ float toF<unsigned short>(unsigned short v) { return bf2f(v); }

// mode: -1 = always run; 0 = run iff x is bf16; 1 = run iff x is f32
template<int K, int M, int RPB, typename AT>
__launch_bounds__(256)
__global__ void mm_kernel(const AT* __restrict__ A, const unsigned short* __restrict__ Wbf,
                          unsigned short* __restrict__ C, int N,
                          const int* __restrict__ flags, int mode) {
    if (mode >= 0 && flags[0] != mode) return;
    __shared__ float As[K][RPB + 16];
    __shared__ unsigned short Ws[K][M];
    int row0 = blockIdx.x * RPB;
    for (int idx = threadIdx.x; idx < RPB * K; idx += 256) {
        int r = idx / K, k = idx - r * K;
        int row = row0 + r;
        As[k][r] = (row < N) ? toF<AT>(A[(size_t)row * K + k]) : 0.f;
    }
    {
        const unsigned int* W32 = (const unsigned int*)Wbf;
        unsigned int* Ws32 = (unsigned int*)&Ws[0][0];
        for (int idx = threadIdx.x; idx < K * M / 2; idx += 256) Ws32[idx] = W32[idx];
    }
    __syncthreads();
    constexpr int CG = M / 4;
    int cg = threadIdx.x % CG;
    int rg = threadIdx.x / CG;
    int r = rg * 4, c = cg * 4;
    float acc[4][4] = {};
    #pragma unroll 4
    for (int k = 0; k < K; ++k) {
        float4 a = *(const float4*)&As[k][r];
        ushort4 wq = *(const ushort4*)&Ws[k][c];
        float w0 = bf2f(wq.x), w1 = bf2f(wq.y), w2 = bf2f(wq.z), w3 = bf2f(wq.w);
        acc[0][0] += a.x * w0; acc[0][1] += a.x * w1; acc[0][2] += a.x * w2; acc[0][3] += a.x * w3;
        acc[1][0] += a.y * w0; acc[1][1] += a.y * w1; acc[1][2] += a.y * w2; acc[1][3] += a.y * w3;
        acc[2][0] += a.z * w0; acc[2][1] += a.z * w1; acc[2][2] += a.z * w2; acc[2][3] += a.z * w3;
        acc[3][0] += a.w * w0; acc[3][1] += a.w * w1; acc[3][2] += a.w * w2; acc[3][3] += a.w * w3;
    }
    #pragma unroll
    for (int i = 0; i < 4; ++i) {
        int row = row0 + r + i;
        if (row < N) {
            ushort4 v;
            v.x = f2bf(acc[i][0]); v.y = f2bf(acc[i][1]);
            v.z = f2bf(acc[i][2]); v.w = f2bf(acc[i][3]);
            *(ushort4*)&C[(size_t)row * M + c] = v;
        }
    }
}

// ---------------- aggregation + optional ReLU/LN ----------------
// One wave per node; HALF-WAVE per edge (2 edges concurrently), LDS-staged
// (src,norm) pairs — no shuffles in the hot loop.
// out[i] = sum_{e: dst=i} h[src_e]*dinv[src_e]*dinv[i] + h[i]*dinv[i]^2 + b

template<int H, bool RELU_LN, bool EMB>
__launch_bounds__(256)
__global__ void agg_kernel(const unsigned short* __restrict__ h,
                           const int* __restrict__ indptr,
                           const int* __restrict__ csr_src,
                           const float* __restrict__ dinv,
                           const float* __restrict__ bias,
                           const float* __restrict__ gamma,
                           const float* __restrict__ beta,
                           unsigned short* __restrict__ out,
                           void* __restrict__ out_emb,
                           int N, const int* __restrict__ flags) {
    constexpr int VPL = H / 32;                 // channels per lane: 4 (H=128), 2 (H=64)
    __shared__ int   lsrc[4][64];
    __shared__ float lnrm[4][64];
    int w = threadIdx.x >> 6;
    int lane = threadIdx.x & 63;
    int hl = lane >> 5;                         // half-wave id: which edge of a pair
    int node = blockIdx.x * 4 + w;
    if (node >= N) return;
    float di = dinv[node];
    int c0 = (lane & 31) * VPL;
    float acc[VPL];
    {   // self loop (weight 0 on upper half so it's counted once)
        float sw = hl ? 0.f : di * di;
        const unsigned short* r = h + (size_t)node * H + c0;
        if constexpr (VPL == 4) {
            uint2 u = *(const uint2*)r;
            acc[0] = bf2f((unsigned short)(u.x & 0xffff)) * sw;
            acc[1] = bf2f((unsigned short)(u.x >> 16)) * sw;
            acc[2] = bf2f((unsigned short)(u.y & 0xffff)) * sw;
            acc[3] = bf2f((unsigned short)(u.y >> 16)) * sw;
        } else {
            unsigned int u = *(const unsigned int*)r;
            acc[0] = bf2f((unsigned short)(u & 0xffff)) * sw;
            acc[1] = bf2f((unsigned short)(u >> 16)) * sw;
        }
    }
    int beg = indptr[node], end = indptr[node + 1];
    for (int base = beg; base < end; base += 64) {
        int m = end - base; if (m > 64) m = 64;
        if (lane < m) {
            int s = csr_src[base + lane];
            if ((unsigned)s >= (unsigned)N) s = 0;
            lsrc[w][lane] = s;
            lnrm[w][lane] = dinv[s] * di;
        }
        // per-wave LDS slice: same-wave DS ordering, no barrier needed
        int j = hl;
        for (; j + 2 < m; j += 4) {             // 2 edges per half = 4 in flight
            int s0 = lsrc[w][j], s1 = lsrc[w][j + 2];
            float n0 = lnrm[w][j], n1 = lnrm[w][j + 2];
            const unsigned short* r0 = h + (size_t)s0 * H + c0;
            const unsigned short* r1 = h + (size_t)s1 * H + c0;
            if constexpr (VPL == 4) {
                uint2 u0 = *(const uint2*)r0;
                uint2 u1 = *(const uint2*)r1;
                acc[0] += bf2f((unsigned short)(u0.x & 0xffff)) * n0
                        + bf2f((unsigned short)(u1.x & 0xffff)) * n1;
                acc[1] += bf2f((unsigned short)(u0.x >> 16)) * n0
                        + bf2f((unsigned short)(u1.x >> 16)) * n1;
                acc[2] += bf2f((unsigned short)(u0.y & 0xffff)) * n0
                        + bf2f((unsigned short)(u1.y & 0xffff)) * n1;
                acc[3] += bf2f((unsigned short)(u0.y >> 16)) * n0
                        + bf2f((unsigned short)(u1.y >> 16)) * n1;
            } else {
                unsigned int u0 = *(const unsigned int*)r0;
                unsigned int u1 = *(const unsigned int*)r1;
                acc[0] += bf2f((unsigned short)(u0 & 0xffff)) * n0
                        + bf2f((unsigned short)(u1 & 0xffff)) * n1;
                acc[1] += bf2f((unsigned short)(u0 >> 16)) * n0
                        + bf2f((unsigned short)(u1 >> 16)) * n1;
            }
        }
        if (j < m) {
            int s0 = lsrc[w][j];
            float n0 = lnrm[w][j];
            const unsigned short* r0 = h + (size_t)s0 * H + c0;
            if constexpr (VPL == 4) {
                uint2 u0 = *(const uint2*)r0;
                acc[0] += bf2f((unsigned short)(u0.x & 0xffff)) * n0;
                acc[1] += bf2f((unsigned short)(u0.x >> 16)) * n0;
                acc[2] += bf2f((unsigned short)(u0.y & 0xffff)) * n0;
                acc[3] += bf2f((unsigned short)(u0.y >> 16)) * n0;
            } else {
                unsigned int u0 = *(const unsigned int*)r0;
                acc[0] += bf2f((unsigned short)(u0 & 0xffff)) * n0;
                acc[1] += bf2f((unsigned short)(u0 >> 16)) * n0;
            }
        }
    }
    // combine the two half-wave partial sums (both halves end with full sums)
    #pragma unroll
    for (int v = 0; v < VPL; ++v) acc[v] += __shfl_xor(acc[v], 32, 64);
    #pragma unroll
    for (int v = 0; v < VPL; ++v) acc[v] += bias[c0 + v];
    if constexpr (RELU_LN) {
        #pragma unroll
        for (int v = 0; v < VPL; ++v) acc[v] = fmaxf(acc[v], 0.f);
        float s = 0.f, sq = 0.f;
        #pragma unroll
        for (int v = 0; v < VPL; ++v) { s += acc[v]; sq += acc[v] * acc[v]; }
        #pragma unroll
        for (int off = 16; off >= 1; off >>= 1) {   // reduce within each half only
            s += __shfl_xor(s, off, 64);
            sq += __shfl_xor(sq, off, 64);
        }
        float mu = s * (1.0f / H);
        float var = fmaxf(sq * (1.0f / H) - mu * mu, 0.f);
        float inv = 1.0f / sqrtf(var + 1e-5f);
        #pragma unroll
        for (int v = 0; v < VPL; ++v)
            acc[v] = (acc[v] - mu) * inv * gamma[c0 + v] + beta[c0 + v];
    }
    if (hl == 0) {
        unsigned short* orow = out + (size_t)node * H + c0;
        if constexpr (VPL == 4) {
            uint2 p; p.x = packbf(acc[0], acc[1]); p.y = packbf(acc[2], acc[3]);
            *(uint2*)orow = p;
        } else {
            *(unsigned int*)orow = packbf(acc[0], acc[1]);
        }
        if constexpr (EMB) {
            if (flags[0]) {
                float* o = (float*)out_emb + (size_t)node * H + c0;
                if constexpr (VPL == 4) *(float4*)o = make_float4(acc[0], acc[1], acc[2], acc[3]);
                else                    *(float2*)o = make_float2(acc[0], acc[1]);
            } else {
                unsigned short* o = (unsigned short*)out_emb + (size_t)node * H + c0;
                if constexpr (VPL == 4) {
                    uint2 p; p.x = packbf(acc[0], acc[1]); p.y = packbf(acc[2], acc[3]);
                    *(uint2*)o = p;
                } else {
                    *(unsigned int*)o = packbf(acc[0], acc[1]);
                }
            }
        }
    }
}

// ---------------- post-mp head: LDS-tiled GEMM + log_softmax ----------------
// 64 rows/block, 256 threads. Phase1: T = relu(E)@Wp1+b1 (4x4 reg tiles).
// Phase2: U = T@Wp2+b2 (4 threads/row, 10 outputs each). Phase3: log_softmax.

__launch_bounds__(256)
__global__ void head_kernel(const unsigned short* __restrict__ emb,
                            const float* __restrict__ Wp1,
                            const float* __restrict__ bp1,
                            const float* __restrict__ Wp2,
                            const float* __restrict__ bp2,
                            void* __restrict__ d_out, int N,
                            const int* __restrict__ flags) {
    __shared__ float Est[64][68];     // [k][row], relu'd
    __shared__ float W1s[64][64];     // [k][c]
    __shared__ float Tst[64][68];     // [c][row]
    __shared__ float W2s[64][OUTD];   // [c][o]
    __shared__ float b1s[64];
    __shared__ float b2s[OUTD];
    int tid = threadIdx.x;
    int row0 = blockIdx.x * 64;
    for (int i = tid; i < 64 * 64; i += 256) W1s[i >> 6][i & 63] = Wp1[i];
    for (int i = tid; i < 64 * OUTD; i += 256) W2s[i / OUTD][i % OUTD] = Wp2[i];
    if (tid < 64) b1s[tid] = bp1[tid];
    if (tid < OUTD) b2s[tid] = bp2[tid];
    for (int i = tid; i < 64 * 32; i += 256) {
        int r = i >> 5, kk = i & 31;
        int row = row0 + r;
        unsigned int u = (row < N) ? *(const unsigned int*)&emb[(size_t)row * 64 + kk * 2] : 0u;
        Est[kk * 2][r]     = fmaxf(bf2f((unsigned short)(u & 0xffff)), 0.f);
        Est[kk * 2 + 1][r] = fmaxf(bf2f((unsigned short)(u >> 16)), 0.f);
    }
    __syncthreads();
    // phase 1
    {
        int rg = tid >> 4, cg = tid & 15;
        int r = rg * 4, c = cg * 4;
        float acc[4][4];
        #pragma unroll
        for (int i = 0; i < 4; ++i)
            #pragma unroll
            for (int jj = 0; jj < 4; ++jj) acc[i][jj] = b1s[c + jj];
        #pragma unroll 4
        for (int k = 0; k < 64; ++k) {
            float4 a = *(const float4*)&Est[k][r];
            float4 wv = *(const float4*)&W1s[k][c];
            acc[0][0] += a.x * wv.x; acc[0][1] += a.x * wv.y; acc[0][2] += a.x * wv.z; acc[0][3] += a.x * wv.w;
            acc[1][0] += a.y * wv.x; acc[1][1] += a.y * wv.y; acc[1][2] += a.y * wv.z; acc[1][3] += a.y * wv.w;
            acc[2][0] += a.z * wv.x; acc[2][1] += a.z * wv.y; acc[2][2] += a.z * wv.z; acc[2][3] += a.z * wv.w;
            acc[3][0] += a.w * wv.x; acc[3][1] += a.w * wv.y; acc[3][2] += a.w * wv.z; acc[3][3] += a.w * wv.w;
        }
        #pragma unroll
        for (int i = 0; i < 4; ++i)
            #pragma unroll
            for (int jj = 0; jj < 4; ++jj) Tst[c + jj][r + i] = acc[i][jj];
    }
    __syncthreads();
    // phase 2 + 3
    int row = tid >> 2, tc = tid & 3, o0 = tc * 10;
    int node = row0 + row;
    float u[10];
    #pragma unroll
    for (int o = 0; o < 10; ++o) u[o] = b2s[o0 + o];
    for (int c2 = 0; c2 < 64; ++c2) {
        float tv = Tst[c2][row];
        const float2* wp = (const float2*)&W2s[c2][o0];
        #pragma unroll
        for (int o2 = 0; o2 < 5; ++o2) {
            float2 wv = wp[o2];
            u[o2 * 2]     += tv * wv.x;
            u[o2 * 2 + 1] += tv * wv.y;
        }
    }
    float mx = u[0];
    #pragma unroll
    for (int o = 1; o < 10; ++o) mx = fmaxf(mx, u[o]);
    mx = fmaxf(mx, __shfl_xor(mx, 1, 64));
    mx = fmaxf(mx, __shfl_xor(mx, 2, 64));
    float sum = 0.f;
    #pragma unroll
    for (int o = 0; o < 10; ++o) sum += __expf(u[o] - mx);
    sum += __shfl_xor(sum, 1, 64);
    sum += __shfl_xor(sum, 2, 64);
    float lse = mx + __logf(sum);
    if (node < N) {
        if (flags[0]) {
            float* base = (float*)d_out + (size_t)N * HID2;
            float* op = base + (size_t)node * OUTD + o0;
            #pragma unroll
            for (int o = 0; o < 10; ++o) op[o] = u[o] - lse;
        } else {
            unsigned short* base = (unsigned short*)d_out + (size_t)N * HID2;
            unsigned int* op = (unsigned int*)(base + (size_t)node * OUTD + o0);
            #pragma unroll
            for (int o2 = 0; o2 < 5; ++o2)
                op[o2] = packbf(u[o2 * 2] - lse, u[o2 * 2 + 1] - lse);
        }
    }
}

// ---------------- launch ----------------

extern "C" void kernel_launch(void* const* d_in, const int* in_sizes, int n_in,
                              void* d_out, int out_size, void* d_ws, size_t ws_size,
                              hipStream_t stream) {
    const unsigned short* xu = (const unsigned short*)d_in[0];
    const float*          xf = (const float*)d_in[0];
    const int*            ei = (const int*)d_in[1];

    const int N = in_sizes[0] / DIN;   // 50000
    const int E = in_sizes[1] / 2;     // 800000

    size_t off = 0;
    auto take = [&](size_t bytes) {
        size_t cur = off;
        off += (bytes + 255) & ~(size_t)255;
        return cur;
    };
    char* ws = (char*)d_ws;
    int*   flags   = (int*)  (ws + take(256));
    int*   cnt     = (int*)  (ws + take((size_t)N * 4));
    float* dinv    = (float*)(ws + take((size_t)N * 4));
    int*   indptr  = (int*)  (ws + take((size_t)(N + 1) * 4));
    int*   cursor  = (int*)  (ws + take((size_t)N * 4));
    int*   csr_src = (int*)  (ws + take((size_t)E * 4));
    unsigned short* wbf = (unsigned short*)(ws + take(32768 * 2));
    float*          wf  = (float*)         (ws + take(8192 * 4));
    unsigned short* hbuf = (unsigned short*)(ws + take((size_t)N * DIN * 2));
    unsigned short* abuf = (unsigned short*)(ws + take((size_t)N * DIN * 2));
    (void)ws_size; (void)n_in; (void)out_size;

    const int TB = 256;
    dim3 blk(TB);

    detect_kernel<<<dim3(1), blk, 0, stream>>>(xu, ei, flags);
    init_cnt_kernel<<<dim3((N + TB - 1) / TB), blk, 0, stream>>>(cnt, N);
    hist_kernel<<<dim3((E + TB - 1) / TB), blk, 0, stream>>>(ei, cnt, E, N, flags);
    scan_kernel<<<dim3(1), dim3(1024), 0, stream>>>(cnt, indptr, cursor, dinv, N);
    fill_kernel<<<dim3((E + TB - 1) / TB), blk, 0, stream>>>(ei, cursor, csr_src, E, N, flags);

    WCvt w;
    int bfoff = 0, foff = 0;
    int offs[14];
    for (int a = 0; a < 14; ++a) {
        int idx = a + 2;
        w.p[a] = d_in[idx];
        w.sz[a] = in_sizes[idx];
        int tobf = (idx == 2 || idx == 4 || idx == 6) ? 1 : 0;
        w.tobf[a] = tobf;
        if (tobf) { w.off[a] = bfoff; bfoff += in_sizes[idx]; }
        else      { w.off[a] = foff;  foff  += in_sizes[idx]; }
        offs[a] = w.off[a];
    }
    wcvt_kernel<<<dim3(64), blk, 0, stream>>>(w, wbf, wf, flags);

    unsigned short* W1b = wbf + offs[0];
    unsigned short* W2b = wbf + offs[2];
    unsigned short* W3b = wbf + offs[4];
    float* b1f  = wf + offs[1];
    float* b2f  = wf + offs[3];
    float* b3f  = wf + offs[5];
    float* g1f  = wf + offs[6];
    float* be1f = wf + offs[7];
    float* g2f  = wf + offs[8];
    float* be2f = wf + offs[9];
    float* Wp1f = wf + offs[10];
    float* bp1f = wf + offs[11];
    float* Wp2f = wf + offs[12];
    float* bp2f = wf + offs[13];

    // layer 1 (dual-dtype x; exactly one variant runs)
    mm_kernel<DIN, HID1, 32, unsigned short><<<dim3((N + 31) / 32), blk, 0, stream>>>(
        xu, W1b, hbuf, N, flags, 0);
    mm_kernel<DIN, HID1, 32, float><<<dim3((N + 31) / 32), blk, 0, stream>>>(
        xf, W1b, hbuf, N, flags, 1);
    agg_kernel<HID1, true, false><<<dim3((N + 3) / 4), blk, 0, stream>>>(
        hbuf, indptr, csr_src, dinv, b1f, g1f, be1f, abuf, nullptr, N, flags);

    // layer 2
    mm_kernel<HID1, HID2, 64, unsigned short><<<dim3((N + 63) / 64), blk, 0, stream>>>(
        abuf, W2b, hbuf, N, flags, -1);
    agg_kernel<HID2, true, false><<<dim3((N + 3) / 4), blk, 0, stream>>>(
        hbuf, indptr, csr_src, dinv, b2f, g2f, be2f, abuf, nullptr, N, flags);

    // layer 3 -> emb
    mm_kernel<HID2, HID2, 64, unsigned short><<<dim3((N + 63) / 64), blk, 0, stream>>>(
        abuf, W3b, hbuf, N, flags, -1);
    agg_kernel<HID2, false, true><<<dim3((N + 3) / 4), blk, 0, stream>>>(
        hbuf, indptr, csr_src, dinv, b3f, nullptr, nullptr, abuf, d_out, N, flags);

    // head
    head_kernel<<<dim3((N + 63) / 64), blk, 0, stream>>>(
        abuf, Wp1f, bp1f, Wp2f, bp2f, d_out, N, flags);
}

// Round 4
// 450.719 us; speedup vs baseline: 1.4286x; 1.2642x over previous
//
#include <hip/hip_runtime.h>
#include <hip/hip_bf16.h>

#define DIN 128
#define HID1 128
#define HID2 64
#define OUTD 40

__device__ __forceinline__ float bf2f(unsigned short u) {
    union { unsigned int i; float f; } c;
    c.i = ((unsigned int)u) << 16;
    return c.f;
}
__device__ __forceinline__ unsigned short f2bf(float f) {
    union { float f; unsigned int i; } c; c.f = f;
    unsigned int r = c.i + 0x7FFFu + ((c.i >> 16) & 1u);   // RNE
    return (unsigned short)(r >> 16);
}
__device__ __forceinline__ unsigned int packbf(float lo, float hi) {
    return (unsigned int)f2bf(lo) | ((unsigned int)f2bf(hi) << 16);
}

// ---------------- runtime dtype detection ----------------
// flags[0] = 1 if float tensors are f32, 0 if bf16
// flags[1] = 1 if edge_index is int64, 0 if int32
__global__ void detect_kernel(const unsigned short* __restrict__ xu,
                              const int* __restrict__ ei, int* __restrict__ flags) {
    __shared__ int sh[2];
    if (threadIdx.x < 2) sh[threadIdx.x] = 0;
    __syncthreads();
    int bad = 0;
    for (int i = threadIdx.x; i < 2048; i += 256) {
        float v = bf2f(xu[2 * i]);
        float a = fabsf(v);
        if (!(a <= 1e4f) || (v != 0.f && a < 1e-4f)) bad++;
    }
    int zodd = 0;
    for (int i = threadIdx.x; i < 1024; i += 256)
        if (ei[2 * i + 1] == 0) zodd++;
    atomicAdd(&sh[0], bad);
    atomicAdd(&sh[1], zodd);
    __syncthreads();
    if (threadIdx.x == 0) {
        flags[0] = (sh[0] > 512) ? 1 : 0;
        flags[1] = (sh[1] > 512) ? 1 : 0;
    }
}

__device__ __forceinline__ int get_src(const int* ei, int E, int e, int e64) {
    return e64 ? ei[2 * e] : ei[e];
}
__device__ __forceinline__ int get_dst(const int* ei, int E, int e, int e64) {
    return e64 ? ei[2 * (E + e)] : ei[E + e];
}

// ---------------- graph preprocessing ----------------

__global__ void init_cnt_kernel(int* __restrict__ cnt, int N) {
    int i = blockIdx.x * blockDim.x + threadIdx.x;
    if (i < N) cnt[i] = 0;
}

__global__ void hist_kernel(const int* __restrict__ ei, int* __restrict__ cnt,
                            int E, int N, const int* __restrict__ flags) {
    int e64 = flags[1];
    int e = blockIdx.x * blockDim.x + threadIdx.x;
    if (e < E) {
        int d = get_dst(ei, E, e, e64);
        if ((unsigned)d < (unsigned)N) atomicAdd(&cnt[d], 1);
    }
}

// ---- 3-stage device-wide exclusive scan of cnt -> indptr/cursor (+dinv) ----

__launch_bounds__(256)
__global__ void bsum_kernel(const int* __restrict__ cnt, int* __restrict__ bsum, int N) {
    __shared__ int sh[256];
    int t = threadIdx.x;
    int i = blockIdx.x * 256 + t;
    sh[t] = (i < N) ? cnt[i] : 0;
    __syncthreads();
    #pragma unroll
    for (int off = 128; off >= 1; off >>= 1) {
        if (t < off) sh[t] += sh[t + off];
        __syncthreads();
    }
    if (t == 0) bsum[blockIdx.x] = sh[0];
}

__launch_bounds__(256)
__global__ void bscan_kernel(const int* __restrict__ bsum, int* __restrict__ bbase,
                             int* __restrict__ indptr, int NB, int N) {
    __shared__ int part[256];
    int t = threadIdx.x;
    int CH = (NB + 255) / 256;
    int lo = t * CH, hi = lo + CH; if (hi > NB) hi = NB;
    int s = 0;
    for (int i = lo; i < hi; ++i) s += bsum[i];
    part[t] = s;
    __syncthreads();
    for (int off = 1; off < 256; off <<= 1) {
        int v = (t >= off) ? part[t - off] : 0;
        __syncthreads();
        part[t] += v;
        __syncthreads();
    }
    int run = (t > 0) ? part[t - 1] : 0;
    for (int i = lo; i < hi; ++i) { bbase[i] = run; run += bsum[i]; }
    if (t == 255) indptr[N] = part[255];
}

__launch_bounds__(256)
__global__ void emit_kernel(const int* __restrict__ cnt, const int* __restrict__ bbase,
                            int* __restrict__ indptr, int* __restrict__ cursor,
                            float* __restrict__ dinv, int N) {
    __shared__ int sh[256];
    int t = threadIdx.x;
    int i = blockIdx.x * 256 + t;
    int c = (i < N) ? cnt[i] : 0;
    sh[t] = c;
    __syncthreads();
    for (int off = 1; off < 256; off <<= 1) {
        int v = (t >= off) ? sh[t - off] : 0;
        __syncthreads();
        sh[t] += v;
        __syncthreads();
    }
    if (i < N) {
        int excl = sh[t] - c + bbase[blockIdx.x];
        indptr[i] = excl;
        cursor[i] = excl;
        dinv[i] = 1.0f / sqrtf((float)(c + 1));   // +1 self loop
    }
}

__global__ void fill_kernel(const int* __restrict__ ei, int* __restrict__ cursor,
                            int* __restrict__ csr_src, int E, int N,
                            const int* __restrict__ flags) {
    int e64 = flags[1];
    int e = blockIdx.x * blockDim.x + threadIdx.x;
    if (e < E) {
        int d = get_dst(ei, E, e, e64);
        if ((unsigned)d < (unsigned)N) {
            int s = get_src(ei, E, e, e64);
            if ((unsigned)s >= (unsigned)N) s = 0;
            int p = atomicAdd(&cursor[d], 1);
            csr_src[p] = s;
        }
    }
}

// ---------------- weight conversion into f32 / bf16 arenas ----------------

struct WCvt {
    const void* p[14];
    int sz[14];
    int off[14];
    int tobf[14];
};

__global__ void wcvt_kernel(WCvt w, unsigned short* __restrict__ wbf,
                            float* __restrict__ wf, const int* __restrict__ flags) {
    int xf32 = flags[0];
    int stride = gridDim.x * blockDim.x;
    int tid = blockIdx.x * blockDim.x + threadIdx.x;
    for (int a = 0; a < 14; ++a) {
        const float* pf = (const float*)w.p[a];
        const unsigned short* pb = (const unsigned short*)w.p[a];
        int n = w.sz[a], off = w.off[a], tobf = w.tobf[a];
        for (int i = tid; i < n; i += stride) {
            float v = xf32 ? pf[i] : bf2f(pb[i]);
            if (tobf) wbf[off + i] = f2bf(v);
            else      wf[off + i]  = v;
        }
    }
}

// ---------------- dense matmul: C[N,M](bf16) = A[N,K] x W[K,M](bf16) ----------------

template<typename AT> __device__ __forceinline__ float toF(AT v);
template<> __device__ __forceinline__ float toF<float>(float v) { return v; }
template<> __device__ __forceinline__ float toF<unsigned short>(unsigned short v) { return bf2f(v); }

// mode: -1 = always run; 0 = run iff x is bf16; 1 = run iff x is f32
template<int K, int M, int RPB, typename AT>
__launch_bounds__(256)
__global__ void mm_kernel(const AT* __restrict__ A, const unsigned short* __restrict__ Wbf,
                          unsigned short* __restrict__ C, int N,
                          const int* __restrict__ flags, int mode) {
    if (mode >= 0 && flags[0] != mode) return;
    __shared__ float As[K][RPB + 16];
    __shared__ unsigned short Ws[K][M];
    int row0 = blockIdx.x * RPB;
    for (int idx = threadIdx.x; idx < RPB * K; idx += 256) {
        int r = idx / K, k = idx - r * K;
        int row = row0 + r;
        As[k][r] = (row < N) ? toF<AT>(A[(size_t)row * K + k]) : 0.f;
    }
    {
        const unsigned int* W32 = (const unsigned int*)Wbf;
        unsigned int* Ws32 = (unsigned int*)&Ws[0][0];
        for (int idx = threadIdx.x; idx < K * M / 2; idx += 256) Ws32[idx] = W32[idx];
    }
    __syncthreads();
    constexpr int CG = M / 4;
    int cg = threadIdx.x % CG;
    int rg = threadIdx.x / CG;
    int r = rg * 4, c = cg * 4;
    float acc[4][4] = {};
    #pragma unroll 4
    for (int k = 0; k < K; ++k) {
        float4 a = *(const float4*)&As[k][r];
        ushort4 wq = *(const ushort4*)&Ws[k][c];
        float w0 = bf2f(wq.x), w1 = bf2f(wq.y), w2 = bf2f(wq.z), w3 = bf2f(wq.w);
        acc[0][0] += a.x * w0; acc[0][1] += a.x * w1; acc[0][2] += a.x * w2; acc[0][3] += a.x * w3;
        acc[1][0] += a.y * w0; acc[1][1] += a.y * w1; acc[1][2] += a.y * w2; acc[1][3] += a.y * w3;
        acc[2][0] += a.z * w0; acc[2][1] += a.z * w1; acc[2][2] += a.z * w2; acc[2][3] += a.z * w3;
        acc[3][0] += a.w * w0; acc[3][1] += a.w * w1; acc[3][2] += a.w * w2; acc[3][3] += a.w * w3;
    }
    #pragma unroll
    for (int i = 0; i < 4; ++i) {
        int row = row0 + r + i;
        if (row < N) {
            ushort4 v;
            v.x = f2bf(acc[i][0]); v.y = f2bf(acc[i][1]);
            v.z = f2bf(acc[i][2]); v.w = f2bf(acc[i][3]);
            *(ushort4*)&C[(size_t)row * M + c] = v;
        }
    }
}

// ---------------- aggregation + optional ReLU/LN ----------------
// One wave per node; HALF-WAVE per edge (2 edges concurrently), LDS-staged
// (src,norm) pairs — no shuffles in the hot loop.
// out[i] = sum_{e: dst=i} h[src_e]*dinv[src_e]*dinv[i] + h[i]*dinv[i]^2 + b

template<int H, bool RELU_LN, bool EMB>
__launch_bounds__(256)
__global__ void agg_kernel(const unsigned short* __restrict__ h,
                           const int* __restrict__ indptr,
                           const int* __restrict__ csr_src,
                           const float* __restrict__ dinv,
                           const float* __restrict__ bias,
                           const float* __restrict__ gamma,
                           const float* __restrict__ beta,
                           unsigned short* __restrict__ out,
                           void* __restrict__ out_emb,
                           int N, const int* __restrict__ flags) {
    constexpr int VPL = H / 32;                 // channels per lane: 4 (H=128), 2 (H=64)
    __shared__ int   lsrc[4][64];
    __shared__ float lnrm[4][64];
    int w = threadIdx.x >> 6;
    int lane = threadIdx.x & 63;
    int hl = lane >> 5;                         // half-wave id: which edge of a pair
    int node = blockIdx.x * 4 + w;
    if (node >= N) return;
    float di = dinv[node];
    int c0 = (lane & 31) * VPL;
    float acc[VPL];
    {   // self loop (weight 0 on upper half so it's counted once)
        float sw = hl ? 0.f : di * di;
        const unsigned short* r = h + (size_t)node * H + c0;
        if constexpr (VPL == 4) {
            uint2 u = *(const uint2*)r;
            acc[0] = bf2f((unsigned short)(u.x & 0xffff)) * sw;
            acc[1] = bf2f((unsigned short)(u.x >> 16)) * sw;
            acc[2] = bf2f((unsigned short)(u.y & 0xffff)) * sw;
            acc[3] = bf2f((unsigned short)(u.y >> 16)) * sw;
        } else {
            unsigned int u = *(const unsigned int*)r;
            acc[0] = bf2f((unsigned short)(u & 0xffff)) * sw;
            acc[1] = bf2f((unsigned short)(u >> 16)) * sw;
        }
    }
    int beg = indptr[node], end = indptr[node + 1];
    for (int base = beg; base < end; base += 64) {
        int m = end - base; if (m > 64) m = 64;
        if (lane < m) {
            int s = csr_src[base + lane];
            if ((unsigned)s >= (unsigned)N) s = 0;
            lsrc[w][lane] = s;
            lnrm[w][lane] = dinv[s] * di;
        }
        // per-wave LDS slice: same-wave DS ordering, no barrier needed
        int j = hl;
        for (; j + 2 < m; j += 4) {             // 2 edges per half = 4 in flight
            int s0 = lsrc[w][j], s1 = lsrc[w][j + 2];
            float n0 = lnrm[w][j], n1 = lnrm[w][j + 2];
            const unsigned short* r0 = h + (size_t)s0 * H + c0;
            const unsigned short* r1 = h + (size_t)s1 * H + c0;
            if constexpr (VPL == 4) {
                uint2 u0 = *(const uint2*)r0;
                uint2 u1 = *(const uint2*)r1;
                acc[0] += bf2f((unsigned short)(u0.x & 0xffff)) * n0
                        + bf2f((unsigned short)(u1.x & 0xffff)) * n1;
                acc[1] += bf2f((unsigned short)(u0.x >> 16)) * n0
                        + bf2f((unsigned short)(u1.x >> 16)) * n1;
                acc[2] += bf2f((unsigned short)(u0.y & 0xffff)) * n0
                        + bf2f((unsigned short)(u1.y & 0xffff)) * n1;
                acc[3] += bf2f((unsigned short)(u0.y >> 16)) * n0
                        + bf2f((unsigned short)(u1.y >> 16)) * n1;
            } else {
                unsigned int u0 = *(const unsigned int*)r0;
                unsigned int u1 = *(const unsigned int*)r1;
                acc[0] += bf2f((unsigned short)(u0 & 0xffff)) * n0
                        + bf2f((unsigned short)(u1 & 0xffff)) * n1;
                acc[1] += bf2f((unsigned short)(u0 >> 16)) * n0
                        + bf2f((unsigned short)(u1 >> 16)) * n1;
            }
        }
        if (j < m) {
            int s0 = lsrc[w][j];
            float n0 = lnrm[w][j];
            const unsigned short* r0 = h + (size_t)s0 * H + c0;
            if constexpr (VPL == 4) {
                uint2 u0 = *(const uint2*)r0;
                acc[0] += bf2f((unsigned short)(u0.x & 0xffff)) * n0;
                acc[1] += bf2f((unsigned short)(u0.x >> 16)) * n0;
                acc[2] += bf2f((unsigned short)(u0.y & 0xffff)) * n0;
                acc[3] += bf2f((unsigned short)(u0.y >> 16)) * n0;
            } else {
                unsigned int u0 = *(const unsigned int*)r0;
                acc[0] += bf2f((unsigned short)(u0 & 0xffff)) * n0;
                acc[1] += bf2f((unsigned short)(u0 >> 16)) * n0;
            }
        }
    }
    // combine the two half-wave partial sums (both halves end with full sums)
    #pragma unroll
    for (int v = 0; v < VPL; ++v) acc[v] += __shfl_xor(acc[v], 32, 64);
    #pragma unroll
    for (int v = 0; v < VPL; ++v) acc[v] += bias[c0 + v];
    if constexpr (RELU_LN) {
        #pragma unroll
        for (int v = 0; v < VPL; ++v) acc[v] = fmaxf(acc[v], 0.f);
        float s = 0.f, sq = 0.f;
        #pragma unroll
        for (int v = 0; v < VPL; ++v) { s += acc[v]; sq += acc[v] * acc[v]; }
        #pragma unroll
        for (int off = 16; off >= 1; off >>= 1) {   // reduce within each half only
            s += __shfl_xor(s, off, 64);
            sq += __shfl_xor(sq, off, 64);
        }
        float mu = s * (1.0f / H);
        float var = fmaxf(sq * (1.0f / H) - mu * mu, 0.f);
        float inv = 1.0f / sqrtf(var + 1e-5f);
        #pragma unroll
        for (int v = 0; v < VPL; ++v)
            acc[v] = (acc[v] - mu) * inv * gamma[c0 + v] + beta[c0 + v];
    }
    if (hl == 0) {
        unsigned short* orow = out + (size_t)node * H + c0;
        if constexpr (VPL == 4) {
            uint2 p; p.x = packbf(acc[0], acc[1]); p.y = packbf(acc[2], acc[3]);
            *(uint2*)orow = p;
        } else {
            *(unsigned int*)orow = packbf(acc[0], acc[1]);
        }
        if constexpr (EMB) {
            if (flags[0]) {
                float* o = (float*)out_emb + (size_t)node * H + c0;
                if constexpr (VPL == 4) *(float4*)o = make_float4(acc[0], acc[1], acc[2], acc[3]);
                else                    *(float2*)o = make_float2(acc[0], acc[1]);
            } else {
                unsigned short* o = (unsigned short*)out_emb + (size_t)node * H + c0;
                if constexpr (VPL == 4) {
                    uint2 p; p.x = packbf(acc[0], acc[1]); p.y = packbf(acc[2], acc[3]);
                    *(uint2*)o = p;
                } else {
                    *(unsigned int*)o = packbf(acc[0], acc[1]);
                }
            }
        }
    }
}

// ---------------- post-mp head: LDS-tiled GEMM + log_softmax ----------------
// 64 rows/block, 256 threads. Phase1: T = relu(E)@Wp1+b1 (4x4 reg tiles).
// Phase2: U = T@Wp2+b2 (4 threads/row, 10 outputs each). Phase3: log_softmax.

__launch_bounds__(256)
__global__ void head_kernel(const unsigned short* __restrict__ emb,
                            const float* __restrict__ Wp1,
                            const float* __restrict__ bp1,
                            const float* __restrict__ Wp2,
                            const float* __restrict__ bp2,
                            void* __restrict__ d_out, int N,
                            const int* __restrict__ flags) {
    __shared__ float Est[64][68];     // [k][row], relu'd
    __shared__ float W1s[64][64];     // [k][c]
    __shared__ float Tst[64][68];     // [c][row]
    __shared__ float W2s[64][OUTD];   // [c][o]
    __shared__ float b1s[64];
    __shared__ float b2s[OUTD];
    int tid = threadIdx.x;
    int row0 = blockIdx.x * 64;
    for (int i = tid; i < 64 * 64; i += 256) W1s[i >> 6][i & 63] = Wp1[i];
    for (int i = tid; i < 64 * OUTD; i += 256) W2s[i / OUTD][i % OUTD] = Wp2[i];
    if (tid < 64) b1s[tid] = bp1[tid];
    if (tid < OUTD) b2s[tid] = bp2[tid];
    for (int i = tid; i < 64 * 32; i += 256) {
        int r = i >> 5, kk = i & 31;
        int row = row0 + r;
        unsigned int u = (row < N) ? *(const unsigned int*)&emb[(size_t)row * 64 + kk * 2] : 0u;
        Est[kk * 2][r]     = fmaxf(bf2f((unsigned short)(u & 0xffff)), 0.f);
        Est[kk * 2 + 1][r] = fmaxf(bf2f((unsigned short)(u >> 16)), 0.f);
    }
    __syncthreads();
    // phase 1
    {
        int rg = tid >> 4, cg = tid & 15;
        int r = rg * 4, c = cg * 4;
        float acc[4][4];
        #pragma unroll
        for (int i = 0; i < 4; ++i)
            #pragma unroll
            for (int jj = 0; jj < 4; ++jj) acc[i][jj] = b1s[c + jj];
        #pragma unroll 4
        for (int k = 0; k < 64; ++k) {
            float4 a = *(const float4*)&Est[k][r];
            float4 wv = *(const float4*)&W1s[k][c];
            acc[0][0] += a.x * wv.x; acc[0][1] += a.x * wv.y; acc[0][2] += a.x * wv.z; acc[0][3] += a.x * wv.w;
            acc[1][0] += a.y * wv.x; acc[1][1] += a.y * wv.y; acc[1][2] += a.y * wv.z; acc[1][3] += a.y * wv.w;
            acc[2][0] += a.z * wv.x; acc[2][1] += a.z * wv.y; acc[2][2] += a.z * wv.z; acc[2][3] += a.z * wv.w;
            acc[3][0] += a.w * wv.x; acc[3][1] += a.w * wv.y; acc[3][2] += a.w * wv.z; acc[3][3] += a.w * wv.w;
        }
        #pragma unroll
        for (int i = 0; i < 4; ++i)
            #pragma unroll
            for (int jj = 0; jj < 4; ++jj) Tst[c + jj][r + i] = acc[i][jj];
    }
    __syncthreads();
    // phase 2 + 3
    int row = tid >> 2, tc = tid & 3, o0 = tc * 10;
    int node = row0 + row;
    float u[10];
    #pragma unroll
    for (int o = 0; o < 10; ++o) u[o] = b2s[o0 + o];
    for (int c2 = 0; c2 < 64; ++c2) {
        float tv = Tst[c2][row];
        const float2* wp = (const float2*)&W2s[c2][o0];
        #pragma unroll
        for (int o2 = 0; o2 < 5; ++o2) {
            float2 wv = wp[o2];
            u[o2 * 2]     += tv * wv.x;
            u[o2 * 2 + 1] += tv * wv.y;
        }
    }
    float mx = u[0];
    #pragma unroll
    for (int o = 1; o < 10; ++o) mx = fmaxf(mx, u[o]);
    mx = fmaxf(mx, __shfl_xor(mx, 1, 64));
    mx = fmaxf(mx, __shfl_xor(mx, 2, 64));
    float sum = 0.f;
    #pragma unroll
    for (int o = 0; o < 10; ++o) sum += __expf(u[o] - mx);
    sum += __shfl_xor(sum, 1, 64);
    sum += __shfl_xor(sum, 2, 64);
    float lse = mx + __logf(sum);
    if (node < N) {
        if (flags[0]) {
            float* base = (float*)d_out + (size_t)N * HID2;
            float* op = base + (size_t)node * OUTD + o0;
            #pragma unroll
            for (int o = 0; o < 10; ++o) op[o] = u[o] - lse;
        } else {
            unsigned short* base = (unsigned short*)d_out + (size_t)N * HID2;
            unsigned int* op = (unsigned int*)(base + (size_t)node * OUTD + o0);
            #pragma unroll
            for (int o2 = 0; o2 < 5; ++o2)
                op[o2] = packbf(u[o2 * 2] - lse, u[o2 * 2 + 1] - lse);
        }
    }
}

// ---------------- launch ----------------

extern "C" void kernel_launch(void* const* d_in, const int* in_sizes, int n_in,
                              void* d_out, int out_size, void* d_ws, size_t ws_size,
                              hipStream_t stream) {
    const unsigned short* xu = (const unsigned short*)d_in[0];
    const float*          xf = (const float*)d_in[0];
    const int*            ei = (const int*)d_in[1];

    const int N = in_sizes[0] / DIN;   // 50000
    const int E = in_sizes[1] / 2;     // 800000

    size_t off = 0;
    auto take = [&](size_t bytes) {
        size_t cur = off;
        off += (bytes + 255) & ~(size_t)255;
        return cur;
    };
    char* ws = (char*)d_ws;
    int*   flags   = (int*)  (ws + take(256));
    int*   cnt     = (int*)  (ws + take((size_t)N * 4));
    float* dinv    = (float*)(ws + take((size_t)N * 4));
    int*   indptr  = (int*)  (ws + take((size_t)(N + 1) * 4));
    int*   cursor  = (int*)  (ws + take((size_t)N * 4));
    int*   csr_src = (int*)  (ws + take((size_t)E * 4));
    int*   bsum    = (int*)  (ws + take(((size_t)N / 256 + 2) * 4));
    int*   bbase   = (int*)  (ws + take(((size_t)N / 256 + 2) * 4));
    unsigned short* wbf = (unsigned short*)(ws + take(32768 * 2));
    float*          wf  = (float*)         (ws + take(8192 * 4));
    unsigned short* hbuf = (unsigned short*)(ws + take((size_t)N * DIN * 2));
    unsigned short* abuf = (unsigned short*)(ws + take((size_t)N * DIN * 2));
    (void)ws_size; (void)n_in; (void)out_size;

    const int TB = 256;
    dim3 blk(TB);
    const int NB = (N + 255) / 256;

    detect_kernel<<<dim3(1), blk, 0, stream>>>(xu, ei, flags);
    init_cnt_kernel<<<dim3((N + TB - 1) / TB), blk, 0, stream>>>(cnt, N);
    hist_kernel<<<dim3((E + TB - 1) / TB), blk, 0, stream>>>(ei, cnt, E, N, flags);
    bsum_kernel<<<dim3(NB), blk, 0, stream>>>(cnt, bsum, N);
    bscan_kernel<<<dim3(1), blk, 0, stream>>>(bsum, bbase, indptr, NB, N);
    emit_kernel<<<dim3(NB), blk, 0, stream>>>(cnt, bbase, indptr, cursor, dinv, N);
    fill_kernel<<<dim3((E + TB - 1) / TB), blk, 0, stream>>>(ei, cursor, csr_src, E, N, flags);

    WCvt w;
    int bfoff = 0, foff = 0;
    int offs[14];
    for (int a = 0; a < 14; ++a) {
        int idx = a + 2;
        w.p[a] = d_in[idx];
        w.sz[a] = in_sizes[idx];
        int tobf = (idx == 2 || idx == 4 || idx == 6) ? 1 : 0;
        w.tobf[a] = tobf;
        if (tobf) { w.off[a] = bfoff; bfoff += in_sizes[idx]; }
        else      { w.off[a] = foff;  foff  += in_sizes[idx]; }
        offs[a] = w.off[a];
    }
    wcvt_kernel<<<dim3(64), blk, 0, stream>>>(w, wbf, wf, flags);

    unsigned short* W1b = wbf + offs[0];
    unsigned short* W2b = wbf + offs[2];
    unsigned short* W3b = wbf + offs[4];
    float* b1f  = wf + offs[1];
    float* b2f  = wf + offs[3];
    float* b3f  = wf + offs[5];
    float* g1f  = wf + offs[6];
    float* be1f = wf + offs[7];
    float* g2f  = wf + offs[8];
    float* be2f = wf + offs[9];
    float* Wp1f = wf + offs[10];
    float* bp1f = wf + offs[11];
    float* Wp2f = wf + offs[12];
    float* bp2f = wf + offs[13];

    // layer 1 (dual-dtype x; exactly one variant runs)
    mm_kernel<DIN, HID1, 32, unsigned short><<<dim3((N + 31) / 32), blk, 0, stream>>>(
        xu, W1b, hbuf, N, flags, 0);
    mm_kernel<DIN, HID1, 32, float><<<dim3((N + 31) / 32), blk, 0, stream>>>(
        xf, W1b, hbuf, N, flags, 1);
    agg_kernel<HID1, true, false><<<dim3((N + 3) / 4), blk, 0, stream>>>(
        hbuf, indptr, csr_src, dinv, b1f, g1f, be1f, abuf, nullptr, N, flags);

    // layer 2
    mm_kernel<HID1, HID2, 64, unsigned short><<<dim3((N + 63) / 64), blk, 0, stream>>>(
        abuf, W2b, hbuf, N, flags, -1);
    agg_kernel<HID2, true, false><<<dim3((N + 3) / 4), blk, 0, stream>>>(
        hbuf, indptr, csr_src, dinv, b2f, g2f, be2f, abuf, nullptr, N, flags);

    // layer 3 -> emb
    mm_kernel<HID2, HID2, 64, unsigned short><<<dim3((N + 63) / 64), blk, 0, stream>>>(
        abuf, W3b, hbuf, N, flags, -1);
    agg_kernel<HID2, false, true><<<dim3((N + 3) / 4), blk, 0, stream>>>(
        hbuf, indptr, csr_src, dinv, b3f, nullptr, nullptr, abuf, d_out, N, flags);

    // head
    head_kernel<<<dim3((N + 63) / 64), blk, 0, stream>>>(
        abuf, Wp1f, bp1f, Wp2f, bp2f, d_out, N, flags);
}

// Round 5
// 369.805 us; speedup vs baseline: 1.7412x; 1.2188x over previous
//
#include <hip/hip_runtime.h>
#include <hip/hip_bf16.h>

#define DIN 128
#define HID1 128
#define HID2 64
#define OUTD 40

typedef __attribute__((ext_vector_type(8))) short bf16x8;
typedef __attribute__((ext_vector_type(4))) float f32x4;

__device__ __forceinline__ float bf2f(unsigned short u) {
    union { unsigned int i; float f; } c;
    c.i = ((unsigned int)u) << 16;
    return c.f;
}
__device__ __forceinline__ unsigned short f2bf(float f) {
    union { float f; unsigned int i; } c; c.f = f;
    unsigned int r = c.i + 0x7FFFu + ((c.i >> 16) & 1u);   // RNE
    return (unsigned short)(r >> 16);
}
__device__ __forceinline__ unsigned int packbf(float lo, float hi) {
    return (unsigned int)f2bf(lo) | ((unsigned int)f2bf(hi) << 16);
}

// ---------------- runtime dtype detection ----------------
// flags[0] = 1 if float tensors are f32, 0 if bf16
// flags[1] = 1 if edge_index is int64, 0 if int32
__global__ void detect_kernel(const unsigned short* __restrict__ xu,
                              const int* __restrict__ ei, int* __restrict__ flags) {
    __shared__ int sh[2];
    if (threadIdx.x < 2) sh[threadIdx.x] = 0;
    __syncthreads();
    int bad = 0;
    for (int i = threadIdx.x; i < 2048; i += 256) {
        float v = bf2f(xu[2 * i]);
        float a = fabsf(v);
        if (!(a <= 1e4f) || (v != 0.f && a < 1e-4f)) bad++;
    }
    int zodd = 0;
    for (int i = threadIdx.x; i < 1024; i += 256)
        if (ei[2 * i + 1] == 0) zodd++;
    atomicAdd(&sh[0], bad);
    atomicAdd(&sh[1], zodd);
    __syncthreads();
    if (threadIdx.x == 0) {
        flags[0] = (sh[0] > 512) ? 1 : 0;
        flags[1] = (sh[1] > 512) ? 1 : 0;
    }
}

__device__ __forceinline__ int get_src(const int* ei, int E, int e, int e64) {
    return e64 ? ei[2 * e] : ei[e];
}
__device__ __forceinline__ int get_dst(const int* ei, int E, int e, int e64) {
    return e64 ? ei[2 * (E + e)] : ei[E + e];
}

// ---------------- graph preprocessing ----------------

__global__ void init_cnt_kernel(int* __restrict__ cnt, int N) {
    int i = blockIdx.x * blockDim.x + threadIdx.x;
    if (i < N) cnt[i] = 0;
}

__global__ void hist_kernel(const int* __restrict__ ei, int* __restrict__ cnt,
                            int E, int N, const int* __restrict__ flags) {
    int e64 = flags[1];
    int e = blockIdx.x * blockDim.x + threadIdx.x;
    if (e < E) {
        int d = get_dst(ei, E, e, e64);
        if ((unsigned)d < (unsigned)N) atomicAdd(&cnt[d], 1);
    }
}

// ---- 3-stage device-wide exclusive scan of cnt -> indptr/cursor (+dinv) ----

__launch_bounds__(256)
__global__ void bsum_kernel(const int* __restrict__ cnt, int* __restrict__ bsum, int N) {
    __shared__ int sh[256];
    int t = threadIdx.x;
    int i = blockIdx.x * 256 + t;
    sh[t] = (i < N) ? cnt[i] : 0;
    __syncthreads();
    #pragma unroll
    for (int off = 128; off >= 1; off >>= 1) {
        if (t < off) sh[t] += sh[t + off];
        __syncthreads();
    }
    if (t == 0) bsum[blockIdx.x] = sh[0];
}

__launch_bounds__(256)
__global__ void bscan_kernel(const int* __restrict__ bsum, int* __restrict__ bbase,
                             int* __restrict__ indptr, int NB, int N) {
    __shared__ int part[256];
    int t = threadIdx.x;
    int CH = (NB + 255) / 256;
    int lo = t * CH, hi = lo + CH; if (hi > NB) hi = NB;
    int s = 0;
    for (int i = lo; i < hi; ++i) s += bsum[i];
    part[t] = s;
    __syncthreads();
    for (int off = 1; off < 256; off <<= 1) {
        int v = (t >= off) ? part[t - off] : 0;
        __syncthreads();
        part[t] += v;
        __syncthreads();
    }
    int run = (t > 0) ? part[t - 1] : 0;
    for (int i = lo; i < hi; ++i) { bbase[i] = run; run += bsum[i]; }
    if (t == 255) indptr[N] = part[255];
}

__launch_bounds__(256)
__global__ void emit_kernel(const int* __restrict__ cnt, const int* __restrict__ bbase,
                            int* __restrict__ indptr, int* __restrict__ cursor,
                            float* __restrict__ dinv, int N) {
    __shared__ int sh[256];
    int t = threadIdx.x;
    int i = blockIdx.x * 256 + t;
    int c = (i < N) ? cnt[i] : 0;
    sh[t] = c;
    __syncthreads();
    for (int off = 1; off < 256; off <<= 1) {
        int v = (t >= off) ? sh[t - off] : 0;
        __syncthreads();
        sh[t] += v;
        __syncthreads();
    }
    if (i < N) {
        int excl = sh[t] - c + bbase[blockIdx.x];
        indptr[i] = excl;
        cursor[i] = excl;
        dinv[i] = 1.0f / sqrtf((float)(c + 1));   // +1 self loop
    }
}

// 4 edges/thread: 4 independent atomic round-trips in flight (latency hiding)
__global__ void fill_kernel(const int* __restrict__ ei, int* __restrict__ cursor,
                            int* __restrict__ csr_src, int E, int N,
                            const int* __restrict__ flags) {
    int e64 = flags[1];
    int base = (blockIdx.x * blockDim.x + threadIdx.x) * 4;
    int s[4], p[4], valid[4];
    #pragma unroll
    for (int u = 0; u < 4; ++u) {
        int e = base + u;
        valid[u] = 0;
        if (e < E) {
            int d = get_dst(ei, E, e, e64);
            if ((unsigned)d < (unsigned)N) {
                int sv = get_src(ei, E, e, e64);
                if ((unsigned)sv >= (unsigned)N) sv = 0;
                s[u] = sv;
                p[u] = atomicAdd(&cursor[d], 1);
                valid[u] = 1;
            }
        }
    }
    #pragma unroll
    for (int u = 0; u < 4; ++u)
        if (valid[u]) csr_src[p[u]] = s[u];
}

// ---------------- weight conversion into f32 / bf16 arenas ----------------
// bf16 entries (W1/W2/W3) are stored TRANSPOSED: WT[m][k] = W[k][m] (for MFMA B-frags)

struct WCvt {
    const void* p[14];
    int sz[14];
    int off[14];
    int tobf[14];
    int cols[14];     // cols of W[k][m] for transposed store (tobf only)
};

__global__ void wcvt_kernel(WCvt w, unsigned short* __restrict__ wbf,
                            float* __restrict__ wf, const int* __restrict__ flags) {
    int xf32 = flags[0];
    int stride = gridDim.x * blockDim.x;
    int tid = blockIdx.x * blockDim.x + threadIdx.x;
    for (int a = 0; a < 14; ++a) {
        const float* pf = (const float*)w.p[a];
        const unsigned short* pb = (const unsigned short*)w.p[a];
        int n = w.sz[a], off = w.off[a], tobf = w.tobf[a];
        int cols = w.cols[a];
        int rows = tobf ? (n / cols) : 0;
        for (int i = tid; i < n; i += stride) {
            float v = xf32 ? pf[i] : bf2f(pb[i]);
            if (tobf) {
                int k = i / cols, m = i % cols;
                wbf[off + m * rows + k] = f2bf(v);   // transposed
            } else {
                wf[off + i] = v;
            }
        }
    }
}

// x (f32) -> bf16; only runs when flags[0]==1
__global__ void xcvt_kernel(const float* __restrict__ xf, unsigned short* __restrict__ xbf,
                            int n, const int* __restrict__ flags) {
    if (!flags[0]) return;
    int stride = gridDim.x * blockDim.x;
    for (int i = blockIdx.x * blockDim.x + threadIdx.x; i < n; i += stride)
        xbf[i] = f2bf(xf[i]);
}

// ---------------- MFMA matmul: C[N,M](bf16) = A[N,K](bf16) x W[K,M](bf16) ----------------
// WT arena holds W transposed: WT[m][k], row-major [M][K].
// Block = 256 threads = 4 waves; each wave computes a 16-row strip x M cols.
// A-frag: lane (m=lane&15, q=lane>>4) loads A[row0+w*16+m][k0+q*8 .. +7] (16B global).
// B-frag: lane loads WT[t*16+m][k0+q*8 .. +7] from LDS (K+8 pad -> conflict-free).
// D: col=lane&15, row=q*4+reg (m89-verified layout).

template<int K, int M>
__launch_bounds__(256)
__global__ void mm_mfma_kernel(const unsigned short* __restrict__ A0,
                               const unsigned short* __restrict__ A1,
                               const unsigned short* __restrict__ WT,
                               unsigned short* __restrict__ C, int N,
                               const int* __restrict__ flags, int useAlt) {
    __shared__ unsigned short Ws[M][K + 8];
    const unsigned short* A = (useAlt && flags[0]) ? A1 : A0;
    int tid = threadIdx.x;
    for (int idx = tid; idx < M * K / 8; idx += 256) {
        int r = idx / (K / 8), c8 = idx % (K / 8);
        *(uint4*)&Ws[r][c8 * 8] = *(const uint4*)&WT[r * K + c8 * 8];
    }
    __syncthreads();
    int w = tid >> 6, lane = tid & 63;
    int m = lane & 15, q = lane >> 4;
    int row_a = blockIdx.x * 64 + w * 16 + m;
    if (row_a >= N) row_a = N - 1;              // clamp; garbage rows masked at store
    const unsigned short* arow = A + (size_t)row_a * K;
    f32x4 acc[M / 16];
    #pragma unroll
    for (int t = 0; t < M / 16; ++t) acc[t] = (f32x4){0.f, 0.f, 0.f, 0.f};
    #pragma unroll
    for (int ks = 0; ks < K / 32; ++ks) {
        int k0 = ks * 32 + q * 8;
        bf16x8 a = *(const bf16x8*)&arow[k0];
        #pragma unroll
        for (int t = 0; t < M / 16; ++t) {
            bf16x8 b = *(const bf16x8*)&Ws[t * 16 + m][k0];
            acc[t] = __builtin_amdgcn_mfma_f32_16x16x32_bf16(a, b, acc[t], 0, 0, 0);
        }
    }
    int rbase = blockIdx.x * 64 + w * 16 + q * 4;
    #pragma unroll
    for (int reg = 0; reg < 4; ++reg) {
        int row = rbase + reg;
        if (row < N) {
            #pragma unroll
            for (int t = 0; t < M / 16; ++t)
                C[(size_t)row * M + t * 16 + m] = f2bf(acc[t][reg]);
        }
    }
}

// ---------------- aggregation + optional ReLU/LN ----------------
// One wave per node; HALF-WAVE per edge (2 edges concurrently), LDS-staged
// (src,norm) pairs — no shuffles in the hot loop.
// out[i] = sum_{e: dst=i} h[src_e]*dinv[src_e]*dinv[i] + h[i]*dinv[i]^2 + b

template<int H, bool RELU_LN, bool EMB>
__launch_bounds__(256)
__global__ void agg_kernel(const unsigned short* __restrict__ h,
                           const int* __restrict__ indptr,
                           const int* __restrict__ csr_src,
                           const float* __restrict__ dinv,
                           const float* __restrict__ bias,
                           const float* __restrict__ gamma,
                           const float* __restrict__ beta,
                           unsigned short* __restrict__ out,
                           void* __restrict__ out_emb,
                           int N, const int* __restrict__ flags) {
    constexpr int VPL = H / 32;                 // channels per lane: 4 (H=128), 2 (H=64)
    __shared__ int   lsrc[4][64];
    __shared__ float lnrm[4][64];
    int w = threadIdx.x >> 6;
    int lane = threadIdx.x & 63;
    int hl = lane >> 5;                         // half-wave id: which edge of a pair
    int node = blockIdx.x * 4 + w;
    if (node >= N) return;
    float di = dinv[node];
    int c0 = (lane & 31) * VPL;
    float acc[VPL];
    {   // self loop (weight 0 on upper half so it's counted once)
        float sw = hl ? 0.f : di * di;
        const unsigned short* r = h + (size_t)node * H + c0;
        if constexpr (VPL == 4) {
            uint2 u = *(const uint2*)r;
            acc[0] = bf2f((unsigned short)(u.x & 0xffff)) * sw;
            acc[1] = bf2f((unsigned short)(u.x >> 16)) * sw;
            acc[2] = bf2f((unsigned short)(u.y & 0xffff)) * sw;
            acc[3] = bf2f((unsigned short)(u.y >> 16)) * sw;
        } else {
            unsigned int u = *(const unsigned int*)r;
            acc[0] = bf2f((unsigned short)(u & 0xffff)) * sw;
            acc[1] = bf2f((unsigned short)(u >> 16)) * sw;
        }
    }
    int beg = indptr[node], end = indptr[node + 1];
    for (int base = beg; base < end; base += 64) {
        int m = end - base; if (m > 64) m = 64;
        if (lane < m) {
            int s = csr_src[base + lane];
            if ((unsigned)s >= (unsigned)N) s = 0;
            lsrc[w][lane] = s;
            lnrm[w][lane] = dinv[s] * di;
        }
        // per-wave LDS slice: same-wave DS ordering, no barrier needed
        int j = hl;
        for (; j + 2 < m; j += 4) {             // 2 edges per half = 4 in flight
            int s0 = lsrc[w][j], s1 = lsrc[w][j + 2];
            float n0 = lnrm[w][j], n1 = lnrm[w][j + 2];
            const unsigned short* r0 = h + (size_t)s0 * H + c0;
            const unsigned short* r1 = h + (size_t)s1 * H + c0;
            if constexpr (VPL == 4) {
                uint2 u0 = *(const uint2*)r0;
                uint2 u1 = *(const uint2*)r1;
                acc[0] += bf2f((unsigned short)(u0.x & 0xffff)) * n0
                        + bf2f((unsigned short)(u1.x & 0xffff)) * n1;
                acc[1] += bf2f((unsigned short)(u0.x >> 16)) * n0
                        + bf2f((unsigned short)(u1.x >> 16)) * n1;
                acc[2] += bf2f((unsigned short)(u0.y & 0xffff)) * n0
                        + bf2f((unsigned short)(u1.y & 0xffff)) * n1;
                acc[3] += bf2f((unsigned short)(u0.y >> 16)) * n0
                        + bf2f((unsigned short)(u1.y >> 16)) * n1;
            } else {
                unsigned int u0 = *(const unsigned int*)r0;
                unsigned int u1 = *(const unsigned int*)r1;
                acc[0] += bf2f((unsigned short)(u0 & 0xffff)) * n0
                        + bf2f((unsigned short)(u1 & 0xffff)) * n1;
                acc[1] += bf2f((unsigned short)(u0 >> 16)) * n0
                        + bf2f((unsigned short)(u1 >> 16)) * n1;
            }
        }
        if (j < m) {
            int s0 = lsrc[w][j];
            float n0 = lnrm[w][j];
            const unsigned short* r0 = h + (size_t)s0 * H + c0;
            if constexpr (VPL == 4) {
                uint2 u0 = *(const uint2*)r0;
                acc[0] += bf2f((unsigned short)(u0.x & 0xffff)) * n0;
                acc[1] += bf2f((unsigned short)(u0.x >> 16)) * n0;
                acc[2] += bf2f((unsigned short)(u0.y & 0xffff)) * n0;
                acc[3] += bf2f((unsigned short)(u0.y >> 16)) * n0;
            } else {
                unsigned int u0 = *(const unsigned int*)r0;
                acc[0] += bf2f((unsigned short)(u0 & 0xffff)) * n0;
                acc[1] += bf2f((unsigned short)(u0 >> 16)) * n0;
            }
        }
    }
    // combine the two half-wave partial sums (both halves end with full sums)
    #pragma unroll
    for (int v = 0; v < VPL; ++v) acc[v] += __shfl_xor(acc[v], 32, 64);
    #pragma unroll
    for (int v = 0; v < VPL; ++v) acc[v] += bias[c0 + v];
    if constexpr (RELU_LN) {
        #pragma unroll
        for (int v = 0; v < VPL; ++v) acc[v] = fmaxf(acc[v], 0.f);
        float s = 0.f, sq = 0.f;
        #pragma unroll
        for (int v = 0; v < VPL; ++v) { s += acc[v]; sq += acc[v] * acc[v]; }
        #pragma unroll
        for (int off = 16; off >= 1; off >>= 1) {   // reduce within each half only
            s += __shfl_xor(s, off, 64);
            sq += __shfl_xor(sq, off, 64);
        }
        float mu = s * (1.0f / H);
        float var = fmaxf(sq * (1.0f / H) - mu * mu, 0.f);
        float inv = 1.0f / sqrtf(var + 1e-5f);
        #pragma unroll
        for (int v = 0; v < VPL; ++v)
            acc[v] = (acc[v] - mu) * inv * gamma[c0 + v] + beta[c0 + v];
    }
    if (hl == 0) {
        unsigned short* orow = out + (size_t)node * H + c0;
        if constexpr (VPL == 4) {
            uint2 p; p.x = packbf(acc[0], acc[1]); p.y = packbf(acc[2], acc[3]);
            *(uint2*)orow = p;
        } else {
            *(unsigned int*)orow = packbf(acc[0], acc[1]);
        }
        if constexpr (EMB) {
            if (flags[0]) {
                float* o = (float*)out_emb + (size_t)node * H + c0;
                if constexpr (VPL == 4) *(float4*)o = make_float4(acc[0], acc[1], acc[2], acc[3]);
                else                    *(float2*)o = make_float2(acc[0], acc[1]);
            } else {
                unsigned short* o = (unsigned short*)out_emb + (size_t)node * H + c0;
                if constexpr (VPL == 4) {
                    uint2 p; p.x = packbf(acc[0], acc[1]); p.y = packbf(acc[2], acc[3]);
                    *(uint2*)o = p;
                } else {
                    *(unsigned int*)o = packbf(acc[0], acc[1]);
                }
            }
        }
    }
}

// ---------------- post-mp head: LDS-tiled GEMM + log_softmax ----------------

__launch_bounds__(256)
__global__ void head_kernel(const unsigned short* __restrict__ emb,
                            const float* __restrict__ Wp1,
                            const float* __restrict__ bp1,
                            const float* __restrict__ Wp2,
                            const float* __restrict__ bp2,
                            void* __restrict__ d_out, int N,
                            const int* __restrict__ flags) {
    __shared__ float Est[64][68];     // [k][row], relu'd
    __shared__ float W1s[64][64];     // [k][c]
    __shared__ float Tst[64][68];     // [c][row]
    __shared__ float W2s[64][OUTD];   // [c][o]
    __shared__ float b1s[64];
    __shared__ float b2s[OUTD];
    int tid = threadIdx.x;
    int row0 = blockIdx.x * 64;
    for (int i = tid; i < 64 * 64; i += 256) W1s[i >> 6][i & 63] = Wp1[i];
    for (int i = tid; i < 64 * OUTD; i += 256) W2s[i / OUTD][i % OUTD] = Wp2[i];
    if (tid < 64) b1s[tid] = bp1[tid];
    if (tid < OUTD) b2s[tid] = bp2[tid];
    for (int i = tid; i < 64 * 32; i += 256) {
        int r = i >> 5, kk = i & 31;
        int row = row0 + r;
        unsigned int u = (row < N) ? *(const unsigned int*)&emb[(size_t)row * 64 + kk * 2] : 0u;
        Est[kk * 2][r]     = fmaxf(bf2f((unsigned short)(u & 0xffff)), 0.f);
        Est[kk * 2 + 1][r] = fmaxf(bf2f((unsigned short)(u >> 16)), 0.f);
    }
    __syncthreads();
    // phase 1
    {
        int rg = tid >> 4, cg = tid & 15;
        int r = rg * 4, c = cg * 4;
        float acc[4][4];
        #pragma unroll
        for (int i = 0; i < 4; ++i)
            #pragma unroll
            for (int jj = 0; jj < 4; ++jj) acc[i][jj] = b1s[c + jj];
        #pragma unroll 4
        for (int k = 0; k < 64; ++k) {
            float4 a = *(const float4*)&Est[k][r];
            float4 wv = *(const float4*)&W1s[k][c];
            acc[0][0] += a.x * wv.x; acc[0][1] += a.x * wv.y; acc[0][2] += a.x * wv.z; acc[0][3] += a.x * wv.w;
            acc[1][0] += a.y * wv.x; acc[1][1] += a.y * wv.y; acc[1][2] += a.y * wv.z; acc[1][3] += a.y * wv.w;
            acc[2][0] += a.z * wv.x; acc[2][1] += a.z * wv.y; acc[2][2] += a.z * wv.z; acc[2][3] += a.z * wv.w;
            acc[3][0] += a.w * wv.x; acc[3][1] += a.w * wv.y; acc[3][2] += a.w * wv.z; acc[3][3] += a.w * wv.w;
        }
        #pragma unroll
        for (int i = 0; i < 4; ++i)
            #pragma unroll
            for (int jj = 0; jj < 4; ++jj) Tst[c + jj][r + i] = acc[i][jj];
    }
    __syncthreads();
    // phase 2 + 3
    int row = tid >> 2, tc = tid & 3, o0 = tc * 10;
    int node = row0 + row;
    float u[10];
    #pragma unroll
    for (int o = 0; o < 10; ++o) u[o] = b2s[o0 + o];
    for (int c2 = 0; c2 < 64; ++c2) {
        float tv = Tst[c2][row];
        const float2* wp = (const float2*)&W2s[c2][o0];
        #pragma unroll
        for (int o2 = 0; o2 < 5; ++o2) {
            float2 wv = wp[o2];
            u[o2 * 2]     += tv * wv.x;
            u[o2 * 2 + 1] += tv * wv.y;
        }
    }
    float mx = u[0];
    #pragma unroll
    for (int o = 1; o < 10; ++o) mx = fmaxf(mx, u[o]);
    mx = fmaxf(mx, __shfl_xor(mx, 1, 64));
    mx = fmaxf(mx, __shfl_xor(mx, 2, 64));
    float sum = 0.f;
    #pragma unroll
    for (int o = 0; o < 10; ++o) sum += __expf(u[o] - mx);
    sum += __shfl_xor(sum, 1, 64);
    sum += __shfl_xor(sum, 2, 64);
    float lse = mx + __logf(sum);
    if (node < N) {
        if (flags[0]) {
            float* base = (float*)d_out + (size_t)N * HID2;
            float* op = base + (size_t)node * OUTD + o0;
            #pragma unroll
            for (int o = 0; o < 10; ++o) op[o] = u[o] - lse;
        } else {
            unsigned short* base = (unsigned short*)d_out + (size_t)N * HID2;
            unsigned int* op = (unsigned int*)(base + (size_t)node * OUTD + o0);
            #pragma unroll
            for (int o2 = 0; o2 < 5; ++o2)
                op[o2] = packbf(u[o2 * 2] - lse, u[o2 * 2 + 1] - lse);
        }
    }
}

// ---------------- launch ----------------

extern "C" void kernel_launch(void* const* d_in, const int* in_sizes, int n_in,
                              void* d_out, int out_size, void* d_ws, size_t ws_size,
                              hipStream_t stream) {
    const unsigned short* xu = (const unsigned short*)d_in[0];
    const float*          xf = (const float*)d_in[0];
    const int*            ei = (const int*)d_in[1];

    const int N = in_sizes[0] / DIN;   // 50000
    const int E = in_sizes[1] / 2;     // 800000

    size_t off = 0;
    auto take = [&](size_t bytes) {
        size_t cur = off;
        off += (bytes + 255) & ~(size_t)255;
        return cur;
    };
    char* ws = (char*)d_ws;
    int*   flags   = (int*)  (ws + take(256));
    int*   cnt     = (int*)  (ws + take((size_t)N * 4));
    float* dinv    = (float*)(ws + take((size_t)N * 4));
    int*   indptr  = (int*)  (ws + take((size_t)(N + 1) * 4));
    int*   cursor  = (int*)  (ws + take((size_t)N * 4));
    int*   csr_src = (int*)  (ws + take((size_t)E * 4));
    int*   bsum    = (int*)  (ws + take(((size_t)N / 256 + 2) * 4));
    int*   bbase   = (int*)  (ws + take(((size_t)N / 256 + 2) * 4));
    unsigned short* wbf = (unsigned short*)(ws + take(32768 * 2));
    float*          wf  = (float*)         (ws + take(8192 * 4));
    unsigned short* hbuf = (unsigned short*)(ws + take((size_t)N * DIN * 2));
    unsigned short* abuf = (unsigned short*)(ws + take((size_t)N * DIN * 2));
    (void)ws_size; (void)n_in; (void)out_size;

    const int TB = 256;
    dim3 blk(TB);
    const int NB = (N + 255) / 256;

    detect_kernel<<<dim3(1), blk, 0, stream>>>(xu, ei, flags);
    init_cnt_kernel<<<dim3((N + TB - 1) / TB), blk, 0, stream>>>(cnt, N);
    hist_kernel<<<dim3((E + TB - 1) / TB), blk, 0, stream>>>(ei, cnt, E, N, flags);
    bsum_kernel<<<dim3(NB), blk, 0, stream>>>(cnt, bsum, N);
    bscan_kernel<<<dim3(1), blk, 0, stream>>>(bsum, bbase, indptr, NB, N);
    emit_kernel<<<dim3(NB), blk, 0, stream>>>(cnt, bbase, indptr, cursor, dinv, N);
    fill_kernel<<<dim3((E + 1023) / 1024), blk, 0, stream>>>(ei, cursor, csr_src, E, N, flags);

    // weight conversion: W1/W2/W3 -> bf16 arena TRANSPOSED; rest -> f32 arena
    WCvt w;
    int bfoff = 0, foff = 0;
    int offs[14];
    const int wcols[14] = {HID1, 0, HID2, 0, HID2, 0, 0, 0, 0, 0, 0, 0, 0, 0};
    for (int a = 0; a < 14; ++a) {
        int idx = a + 2;
        w.p[a] = d_in[idx];
        w.sz[a] = in_sizes[idx];
        int tobf = (idx == 2 || idx == 4 || idx == 6) ? 1 : 0;
        w.tobf[a] = tobf;
        w.cols[a] = tobf ? wcols[a] : 1;
        if (tobf) { w.off[a] = bfoff; bfoff += in_sizes[idx]; }
        else      { w.off[a] = foff;  foff  += in_sizes[idx]; }
        offs[a] = w.off[a];
    }
    wcvt_kernel<<<dim3(64), blk, 0, stream>>>(w, wbf, wf, flags);
    // x -> bf16 into abuf (only if x is f32); abuf is free until agg1 writes it
    xcvt_kernel<<<dim3(512), blk, 0, stream>>>(xf, abuf, N * DIN, flags);

    unsigned short* W1t = wbf + offs[0];   // [128][128] transposed
    unsigned short* W2t = wbf + offs[2];   // [64][128] transposed
    unsigned short* W3t = wbf + offs[4];   // [64][64] transposed
    float* b1f  = wf + offs[1];
    float* b2f  = wf + offs[3];
    float* b3f  = wf + offs[5];
    float* g1f  = wf + offs[6];
    float* be1f = wf + offs[7];
    float* g2f  = wf + offs[8];
    float* be2f = wf + offs[9];
    float* Wp1f = wf + offs[10];
    float* bp1f = wf + offs[11];
    float* Wp2f = wf + offs[12];
    float* bp2f = wf + offs[13];

    const int MMG = (N + 63) / 64;

    // layer 1
    mm_mfma_kernel<DIN, HID1><<<dim3(MMG), blk, 0, stream>>>(xu, abuf, W1t, hbuf, N, flags, 1);
    agg_kernel<HID1, true, false><<<dim3((N + 3) / 4), blk, 0, stream>>>(
        hbuf, indptr, csr_src, dinv, b1f, g1f, be1f, abuf, nullptr, N, flags);

    // layer 2
    mm_mfma_kernel<HID1, HID2><<<dim3(MMG), blk, 0, stream>>>(abuf, nullptr, W2t, hbuf, N, flags, 0);
    agg_kernel<HID2, true, false><<<dim3((N + 3) / 4), blk, 0, stream>>>(
        hbuf, indptr, csr_src, dinv, b2f, g2f, be2f, abuf, nullptr, N, flags);

    // layer 3 -> emb
    mm_mfma_kernel<HID2, HID2><<<dim3(MMG), blk, 0, stream>>>(abuf, nullptr, W3t, hbuf, N, flags, 0);
    agg_kernel<HID2, false, true><<<dim3((N + 3) / 4), blk, 0, stream>>>(
        hbuf, indptr, csr_src, dinv, b3f, nullptr, nullptr, abuf, d_out, N, flags);

    // head
    head_kernel<<<dim3((N + 63) / 64), blk, 0, stream>>>(
        abuf, Wp1f, bp1f, Wp2f, bp2f, d_out, N, flags);
}

// Round 7
// 331.890 us; speedup vs baseline: 1.9401x; 1.1142x over previous
//
#include <hip/hip_runtime.h>
#include <hip/hip_bf16.h>

#define DIN 128
#define HID1 128
#define HID2 64
#define OUTD 40

typedef __attribute__((ext_vector_type(8))) short bf16x8;
typedef __attribute__((ext_vector_type(4))) float f32x4;

__device__ __forceinline__ float bf2f(unsigned int u) {
    union { unsigned int i; float f; } c;
    c.i = u << 16;
    return c.f;
}
__device__ __forceinline__ unsigned short f2bf(float f) {
    union { float f; unsigned int i; } c; c.f = f;
    unsigned int r = c.i + 0x7FFFu + ((c.i >> 16) & 1u);   // RNE
    return (unsigned short)(r >> 16);
}
__device__ __forceinline__ unsigned int packbf(float lo, float hi) {
    return (unsigned int)f2bf(lo) | ((unsigned int)f2bf(hi) << 16);
}

// ---------------- runtime dtype detection ----------------
// flags[0] = 1 if float tensors are f32, 0 if bf16
// flags[1] = 1 if edge_index is int64, 0 if int32
__global__ void detect_kernel(const unsigned short* __restrict__ xu,
                              const int* __restrict__ ei, int* __restrict__ flags) {
    __shared__ int sh[2];
    if (threadIdx.x < 2) sh[threadIdx.x] = 0;
    __syncthreads();
    int bad = 0;
    for (int i = threadIdx.x; i < 2048; i += 256) {
        float v = bf2f(xu[2 * i]);
        float a = fabsf(v);
        if (!(a <= 1e4f) || (v != 0.f && a < 1e-4f)) bad++;
    }
    int zodd = 0;
    for (int i = threadIdx.x; i < 1024; i += 256)
        if (ei[2 * i + 1] == 0) zodd++;
    atomicAdd(&sh[0], bad);
    atomicAdd(&sh[1], zodd);
    __syncthreads();
    if (threadIdx.x == 0) {
        flags[0] = (sh[0] > 512) ? 1 : 0;
        flags[1] = (sh[1] > 512) ? 1 : 0;
    }
}

__device__ __forceinline__ int get_src(const int* ei, int E, int e, int e64) {
    return e64 ? ei[2 * e] : ei[e];
}
__device__ __forceinline__ int get_dst(const int* ei, int E, int e, int e64) {
    return e64 ? ei[2 * (E + e)] : ei[E + e];
}

// ---------------- graph preprocessing ----------------

__global__ void init_cnt_kernel(int* __restrict__ cnt, int N) {
    int i = blockIdx.x * blockDim.x + threadIdx.x;
    if (i < N) cnt[i] = 0;
}

// THE single returned-atomic pass: pos[e] = rank of edge e within its dst bucket.
// Doubles as the degree histogram. 4 edges/thread for ILP.
__global__ void pos_kernel(const int* __restrict__ ei, int* __restrict__ cnt,
                           int* __restrict__ pos, int E, int N,
                           const int* __restrict__ flags) {
    int e64 = flags[1];
    int base = (blockIdx.x * blockDim.x + threadIdx.x) * 4;
    #pragma unroll
    for (int u = 0; u < 4; ++u) {
        int e = base + u;
        if (e < E) {
            int d = get_dst(ei, E, e, e64);
            pos[e] = ((unsigned)d < (unsigned)N) ? atomicAdd(&cnt[d], 1) : -1;
        }
    }
}

// ---- 3-stage device-wide exclusive scan of cnt -> indptr (+dinv) ----

__launch_bounds__(256)
__global__ void bsum_kernel(const int* __restrict__ cnt, int* __restrict__ bsum, int N) {
    __shared__ int sh[256];
    int t = threadIdx.x;
    int i = blockIdx.x * 256 + t;
    sh[t] = (i < N) ? cnt[i] : 0;
    __syncthreads();
    #pragma unroll
    for (int off = 128; off >= 1; off >>= 1) {
        if (t < off) sh[t] += sh[t + off];
        __syncthreads();
    }
    if (t == 0) bsum[blockIdx.x] = sh[0];
}

__launch_bounds__(256)
__global__ void bscan_kernel(const int* __restrict__ bsum, int* __restrict__ bbase,
                             int* __restrict__ indptr, int NB, int N) {
    __shared__ int part[256];
    int t = threadIdx.x;
    int CH = (NB + 255) / 256;
    int lo = t * CH, hi = lo + CH; if (hi > NB) hi = NB;
    int s = 0;
    for (int i = lo; i < hi; ++i) s += bsum[i];
    part[t] = s;
    __syncthreads();
    for (int off = 1; off < 256; off <<= 1) {
        int v = (t >= off) ? part[t - off] : 0;
        __syncthreads();
        part[t] += v;
        __syncthreads();
    }
    int run = (t > 0) ? part[t - 1] : 0;
    for (int i = lo; i < hi; ++i) { bbase[i] = run; run += bsum[i]; }
    if (t == 255) indptr[N] = part[255];
}

__launch_bounds__(256)
__global__ void emit_kernel(const int* __restrict__ cnt, const int* __restrict__ bbase,
                            int* __restrict__ indptr, float* __restrict__ dinv, int N) {
    __shared__ int sh[256];
    int t = threadIdx.x;
    int i = blockIdx.x * 256 + t;
    int c = (i < N) ? cnt[i] : 0;
    sh[t] = c;
    __syncthreads();
    for (int off = 1; off < 256; off <<= 1) {
        int v = (t >= off) ? sh[t - off] : 0;
        __syncthreads();
        sh[t] += v;
        __syncthreads();
    }
    if (i < N) {
        int excl = sh[t] - c + bbase[blockIdx.x];
        indptr[i] = excl;
        dinv[i] = 1.0f / sqrtf((float)(c + 1));   // +1 self loop
    }
}

// atomic-free scatter: slot = indptr[dst] + pos[e]
__global__ void scatter_kernel(const int* __restrict__ ei, const int* __restrict__ indptr,
                               const int* __restrict__ pos, int* __restrict__ csr_src,
                               int E, int N, const int* __restrict__ flags) {
    int e64 = flags[1];
    int base = (blockIdx.x * blockDim.x + threadIdx.x) * 4;
    #pragma unroll
    for (int u = 0; u < 4; ++u) {
        int e = base + u;
        if (e < E) {
            int p = pos[e];
            if (p >= 0) {
                int d = get_dst(ei, E, e, e64);
                int s = get_src(ei, E, e, e64);
                if ((unsigned)s >= (unsigned)N) s = 0;
                csr_src[indptr[d] + p] = s;
            }
        }
    }
}

// ---------------- weight conversion into f32 / bf16 arenas ----------------
// bf16 entries (W1/W2/W3) are stored TRANSPOSED: WT[m][k] = W[k][m] (for MFMA B-frags)

struct WCvt {
    const void* p[14];
    int sz[14];
    int off[14];
    int tobf[14];
    int cols[14];
};

__global__ void wcvt_kernel(WCvt w, unsigned short* __restrict__ wbf,
                            float* __restrict__ wf, const int* __restrict__ flags) {
    int xf32 = flags[0];
    int stride = gridDim.x * blockDim.x;
    int tid = blockIdx.x * blockDim.x + threadIdx.x;
    for (int a = 0; a < 14; ++a) {
        const float* pf = (const float*)w.p[a];
        const unsigned short* pb = (const unsigned short*)w.p[a];
        int n = w.sz[a], off = w.off[a], tobf = w.tobf[a];
        int cols = w.cols[a];
        int rows = tobf ? (n / cols) : 0;
        for (int i = tid; i < n; i += stride) {
            float v = xf32 ? pf[i] : bf2f(pb[i]);
            if (tobf) {
                int k = i / cols, m = i % cols;
                wbf[off + m * rows + k] = f2bf(v);   // transposed
            } else {
                wf[off + i] = v;
            }
        }
    }
}

// x (f32) -> bf16; only runs when flags[0]==1
__global__ void xcvt_kernel(const float* __restrict__ xf, unsigned short* __restrict__ xbf,
                            int n, const int* __restrict__ flags) {
    if (!flags[0]) return;
    int stride = gridDim.x * blockDim.x;
    for (int i = blockIdx.x * blockDim.x + threadIdx.x; i < n; i += stride)
        xbf[i] = f2bf(xf[i]);
}

// ---------------- MFMA matmul: C[N,M](bf16) = A[N,K](bf16) x W[K,M](bf16) ----------------

template<int K, int M>
__launch_bounds__(256)
__global__ void mm_mfma_kernel(const unsigned short* __restrict__ A0,
                               const unsigned short* __restrict__ A1,
                               const unsigned short* __restrict__ WT,
                               unsigned short* __restrict__ C, int N,
                               const int* __restrict__ flags, int useAlt) {
    __shared__ unsigned short Ws[M][K + 8];
    const unsigned short* A = (useAlt && flags[0]) ? A1 : A0;
    int tid = threadIdx.x;
    for (int idx = tid; idx < M * K / 8; idx += 256) {
        int r = idx / (K / 8), c8 = idx % (K / 8);
        *(uint4*)&Ws[r][c8 * 8] = *(const uint4*)&WT[r * K + c8 * 8];
    }
    __syncthreads();
    int w = tid >> 6, lane = tid & 63;
    int m = lane & 15, q = lane >> 4;
    int row_a = blockIdx.x * 64 + w * 16 + m;
    if (row_a >= N) row_a = N - 1;              // clamp; garbage rows masked at store
    const unsigned short* arow = A + (size_t)row_a * K;
    f32x4 acc[M / 16];
    #pragma unroll
    for (int t = 0; t < M / 16; ++t) acc[t] = (f32x4){0.f, 0.f, 0.f, 0.f};
    #pragma unroll
    for (int ks = 0; ks < K / 32; ++ks) {
        int k0 = ks * 32 + q * 8;
        bf16x8 a = *(const bf16x8*)&arow[k0];
        #pragma unroll
        for (int t = 0; t < M / 16; ++t) {
            bf16x8 b = *(const bf16x8*)&Ws[t * 16 + m][k0];
            acc[t] = __builtin_amdgcn_mfma_f32_16x16x32_bf16(a, b, acc[t], 0, 0, 0);
        }
    }
    int rbase = blockIdx.x * 64 + w * 16 + q * 4;
    #pragma unroll
    for (int reg = 0; reg < 4; ++reg) {
        int row = rbase + reg;
        if (row < N) {
            #pragma unroll
            for (int t = 0; t < M / 16; ++t)
                C[(size_t)row * M + t * 16 + m] = f2bf(acc[t][reg]);
        }
    }
}

// ---------------- aggregation + optional ReLU/LN ----------------
// One wave per node; QUARTER-WAVE per edge (4 edges concurrently, unroll 2 ->
// 8 row-gathers in flight per wave), 16 lanes x 16B per row gather.
// out[i] = sum_{e: dst=i} h[src_e]*dinv[src_e]*dinv[i] + h[i]*dinv[i]^2 + b

template<int VPL>
__device__ __forceinline__ void gacc(float* acc, const unsigned short* r, float n) {
    if constexpr (VPL == 8) {
        uint4 u = *(const uint4*)r;
        acc[0] += bf2f(u.x & 0xffffu) * n; acc[1] += bf2f(u.x >> 16) * n;
        acc[2] += bf2f(u.y & 0xffffu) * n; acc[3] += bf2f(u.y >> 16) * n;
        acc[4] += bf2f(u.z & 0xffffu) * n; acc[5] += bf2f(u.z >> 16) * n;
        acc[6] += bf2f(u.w & 0xffffu) * n; acc[7] += bf2f(u.w >> 16) * n;
    } else {
        uint2 u = *(const uint2*)r;
        acc[0] += bf2f(u.x & 0xffffu) * n; acc[1] += bf2f(u.x >> 16) * n;
        acc[2] += bf2f(u.y & 0xffffu) * n; acc[3] += bf2f(u.y >> 16) * n;
    }
}

template<int VPL>
__device__ __forceinline__ void gacc2(float* acc, const unsigned short* r0, float n0,
                                      const unsigned short* r1, float n1) {
    if constexpr (VPL == 8) {
        uint4 u0 = *(const uint4*)r0;
        uint4 u1 = *(const uint4*)r1;
        acc[0] += bf2f(u0.x & 0xffffu) * n0 + bf2f(u1.x & 0xffffu) * n1;
        acc[1] += bf2f(u0.x >> 16) * n0 + bf2f(u1.x >> 16) * n1;
        acc[2] += bf2f(u0.y & 0xffffu) * n0 + bf2f(u1.y & 0xffffu) * n1;
        acc[3] += bf2f(u0.y >> 16) * n0 + bf2f(u1.y >> 16) * n1;
        acc[4] += bf2f(u0.z & 0xffffu) * n0 + bf2f(u1.z & 0xffffu) * n1;
        acc[5] += bf2f(u0.z >> 16) * n0 + bf2f(u1.z >> 16) * n1;
        acc[6] += bf2f(u0.w & 0xffffu) * n0 + bf2f(u1.w & 0xffffu) * n1;
        acc[7] += bf2f(u0.w >> 16) * n0 + bf2f(u1.w >> 16) * n1;
    } else {
        uint2 u0 = *(const uint2*)r0;
        uint2 u1 = *(const uint2*)r1;
        acc[0] += bf2f(u0.x & 0xffffu) * n0 + bf2f(u1.x & 0xffffu) * n1;
        acc[1] += bf2f(u0.x >> 16) * n0 + bf2f(u1.x >> 16) * n1;
        acc[2] += bf2f(u0.y & 0xffffu) * n0 + bf2f(u1.y & 0xffffu) * n1;
        acc[3] += bf2f(u0.y >> 16) * n0 + bf2f(u1.y >> 16) * n1;
    }
}

template<int H, bool RELU_LN, bool EMB>
__launch_bounds__(256)
__global__ void agg_kernel(const unsigned short* __restrict__ h,
                           const int* __restrict__ indptr,
                           const int* __restrict__ csr_src,
                           const float* __restrict__ dinv,
                           const float* __restrict__ bias,
                           const float* __restrict__ gamma,
                           const float* __restrict__ beta,
                           unsigned short* __restrict__ out,
                           void* __restrict__ out_emb,
                           int N, const int* __restrict__ flags) {
    constexpr int VPL = H / 16;                 // 8 (H=128), 4 (H=64)
    __shared__ int   lsrc[4][64];
    __shared__ float lnrm[4][64];
    int w = threadIdx.x >> 6;
    int lane = threadIdx.x & 63;
    int ql = lane >> 4;                         // quarter id: which edge of a quad
    int g = lane & 15;
    int node = blockIdx.x * 4 + w;
    if (node >= N) return;
    float di = dinv[node];
    int c0 = g * VPL;
    float acc[VPL];
    #pragma unroll
    for (int v = 0; v < VPL; ++v) acc[v] = 0.f;
    // self loop: quarter 0 only
    gacc<VPL>(acc, h + (size_t)node * H + c0, (ql == 0) ? di * di : 0.f);
    int beg = indptr[node], end = indptr[node + 1];
    for (int base = beg; base < end; base += 64) {
        int m = end - base; if (m > 64) m = 64;
        if (lane < m) {
            int s = csr_src[base + lane];
            if ((unsigned)s >= (unsigned)N) s = 0;
            lsrc[w][lane] = s;
            lnrm[w][lane] = dinv[s] * di;
        }
        // per-wave LDS slice: same-wave DS ordering, no barrier needed
        int j = ql;
        for (; j + 4 < m; j += 8) {             // 2 edges per quarter = 8 in flight
            int s0 = lsrc[w][j], s1 = lsrc[w][j + 4];
            float n0 = lnrm[w][j], n1 = lnrm[w][j + 4];
            gacc2<VPL>(acc, h + (size_t)s0 * H + c0, n0, h + (size_t)s1 * H + c0, n1);
        }
        if (j < m)
            gacc<VPL>(acc, h + (size_t)lsrc[w][j] * H + c0, lnrm[w][j]);
    }
    // combine the four quarter partial sums
    #pragma unroll
    for (int v = 0; v < VPL; ++v) acc[v] += __shfl_xor(acc[v], 16, 64);
    #pragma unroll
    for (int v = 0; v < VPL; ++v) acc[v] += __shfl_xor(acc[v], 32, 64);
    #pragma unroll
    for (int v = 0; v < VPL; ++v) acc[v] += bias[c0 + v];
    if constexpr (RELU_LN) {
        #pragma unroll
        for (int v = 0; v < VPL; ++v) acc[v] = fmaxf(acc[v], 0.f);
        float s = 0.f, sq = 0.f;
        #pragma unroll
        for (int v = 0; v < VPL; ++v) { s += acc[v]; sq += acc[v] * acc[v]; }
        #pragma unroll
        for (int off = 8; off >= 1; off >>= 1) {   // reduce within 16-lane group
            s += __shfl_xor(s, off, 64);
            sq += __shfl_xor(sq, off, 64);
        }
        float mu = s * (1.0f / H);
        float var = fmaxf(sq * (1.0f / H) - mu * mu, 0.f);
        float inv = 1.0f / sqrtf(var + 1e-5f);
        #pragma unroll
        for (int v = 0; v < VPL; ++v)
            acc[v] = (acc[v] - mu) * inv * gamma[c0 + v] + beta[c0 + v];
    }
    if (ql == 0) {
        unsigned short* orow = out + (size_t)node * H + c0;
        if constexpr (VPL == 8) {
            uint4 p;
            p.x = packbf(acc[0], acc[1]); p.y = packbf(acc[2], acc[3]);
            p.z = packbf(acc[4], acc[5]); p.w = packbf(acc[6], acc[7]);
            *(uint4*)orow = p;
        } else {
            uint2 p; p.x = packbf(acc[0], acc[1]); p.y = packbf(acc[2], acc[3]);
            *(uint2*)orow = p;
        }
        if constexpr (EMB) {
            if (flags[0]) {
                float* o = (float*)out_emb + (size_t)node * H + c0;
                #pragma unroll
                for (int v4 = 0; v4 < VPL / 4; ++v4)
                    *(float4*)(o + v4 * 4) = make_float4(acc[v4 * 4], acc[v4 * 4 + 1],
                                                         acc[v4 * 4 + 2], acc[v4 * 4 + 3]);
            } else {
                unsigned short* o = (unsigned short*)out_emb + (size_t)node * H + c0;
                #pragma unroll
                for (int v2 = 0; v2 < VPL / 2; ++v2)
                    ((unsigned int*)o)[v2] = packbf(acc[v2 * 2], acc[v2 * 2 + 1]);
            }
        }
    }
}

// ---------------- post-mp head: LDS-tiled GEMM + log_softmax ----------------

__launch_bounds__(256)
__global__ void head_kernel(const unsigned short* __restrict__ emb,
                            const float* __restrict__ Wp1,
                            const float* __restrict__ bp1,
                            const float* __restrict__ Wp2,
                            const float* __restrict__ bp2,
                            void* __restrict__ d_out, int N,
                            const int* __restrict__ flags) {
    __shared__ float Est[64][68];     // [k][row], relu'd
    __shared__ float W1s[64][64];     // [k][c]
    __shared__ float Tst[64][68];     // [c][row]
    __shared__ float W2s[64][OUTD];   // [c][o]
    __shared__ float b1s[64];
    __shared__ float b2s[OUTD];
    int tid = threadIdx.x;
    int row0 = blockIdx.x * 64;
    for (int i = tid; i < 64 * 64; i += 256) W1s[i >> 6][i & 63] = Wp1[i];
    for (int i = tid; i < 64 * OUTD; i += 256) W2s[i / OUTD][i % OUTD] = Wp2[i];
    if (tid < 64) b1s[tid] = bp1[tid];
    if (tid < OUTD) b2s[tid] = bp2[tid];
    for (int i = tid; i < 64 * 32; i += 256) {
        int r = i >> 5, kk = i & 31;
        int row = row0 + r;
        unsigned int u = (row < N) ? *(const unsigned int*)&emb[(size_t)row * 64 + kk * 2] : 0u;
        Est[kk * 2][r]     = fmaxf(bf2f(u & 0xffffu), 0.f);
        Est[kk * 2 + 1][r] = fmaxf(bf2f(u >> 16), 0.f);
    }
    __syncthreads();
    // phase 1
    {
        int rg = tid >> 4, cg = tid & 15;
        int r = rg * 4, c = cg * 4;
        float acc[4][4];
        #pragma unroll
        for (int i = 0; i < 4; ++i)
            #pragma unroll
            for (int jj = 0; jj < 4; ++jj) acc[i][jj] = b1s[c + jj];
        #pragma unroll 4
        for (int k = 0; k < 64; ++k) {
            float4 a = *(const float4*)&Est[k][r];
            float4 wv = *(const float4*)&W1s[k][c];
            acc[0][0] += a.x * wv.x; acc[0][1] += a.x * wv.y; acc[0][2] += a.x * wv.z; acc[0][3] += a.x * wv.w;
            acc[1][0] += a.y * wv.x; acc[1][1] += a.y * wv.y; acc[1][2] += a.y * wv.z; acc[1][3] += a.y * wv.w;
            acc[2][0] += a.z * wv.x; acc[2][1] += a.z * wv.y; acc[2][2] += a.z * wv.z; acc[2][3] += a.z * wv.w;
            acc[3][0] += a.w * wv.x; acc[3][1] += a.w * wv.y; acc[3][2] += a.w * wv.z; acc[3][3] += a.w * wv.w;
        }
        #pragma unroll
        for (int i = 0; i < 4; ++i)
            #pragma unroll
            for (int jj = 0; jj < 4; ++jj) Tst[c + jj][r + i] = acc[i][jj];
    }
    __syncthreads();
    // phase 2 + 3
    int row = tid >> 2, tc = tid & 3, o0 = tc * 10;
    int node = row0 + row;
    float u[10];
    #pragma unroll
    for (int o = 0; o < 10; ++o) u[o] = b2s[o0 + o];
    for (int c2 = 0; c2 < 64; ++c2) {
        float tv = Tst[c2][row];
        const float2* wp = (const float2*)&W2s[c2][o0];
        #pragma unroll
        for (int o2 = 0; o2 < 5; ++o2) {
            float2 wv = wp[o2];
            u[o2 * 2]     += tv * wv.x;
            u[o2 * 2 + 1] += tv * wv.y;
        }
    }
    float mx = u[0];
    #pragma unroll
    for (int o = 1; o < 10; ++o) mx = fmaxf(mx, u[o]);
    mx = fmaxf(mx, __shfl_xor(mx, 1, 64));
    mx = fmaxf(mx, __shfl_xor(mx, 2, 64));
    float sum = 0.f;
    #pragma unroll
    for (int o = 0; o < 10; ++o) sum += __expf(u[o] - mx);
    sum += __shfl_xor(sum, 1, 64);
    sum += __shfl_xor(sum, 2, 64);
    float lse = mx + __logf(sum);
    if (node < N) {
        if (flags[0]) {
            float* base = (float*)d_out + (size_t)N * HID2;
            float* op = base + (size_t)node * OUTD + o0;
            #pragma unroll
            for (int o = 0; o < 10; ++o) op[o] = u[o] - lse;
        } else {
            unsigned short* base = (unsigned short*)d_out + (size_t)N * HID2;
            unsigned int* op = (unsigned int*)(base + (size_t)node * OUTD + o0);
            #pragma unroll
            for (int o2 = 0; o2 < 5; ++o2)
                op[o2] = packbf(u[o2 * 2] - lse, u[o2 * 2 + 1] - lse);
        }
    }
}

// ---------------- launch ----------------

extern "C" void kernel_launch(void* const* d_in, const int* in_sizes, int n_in,
                              void* d_out, int out_size, void* d_ws, size_t ws_size,
                              hipStream_t stream) {
    const unsigned short* xu = (const unsigned short*)d_in[0];
    const float*          xf = (const float*)d_in[0];
    const int*            ei = (const int*)d_in[1];

    const int N = in_sizes[0] / DIN;   // 50000
    const int E = in_sizes[1] / 2;     // 800000

    size_t off = 0;
    auto take = [&](size_t bytes) {
        size_t cur = off;
        off += (bytes + 255) & ~(size_t)255;
        return cur;
    };
    char* ws = (char*)d_ws;
    int*   flags   = (int*)  (ws + take(256));
    int*   cnt     = (int*)  (ws + take((size_t)N * 4));
    float* dinv    = (float*)(ws + take((size_t)N * 4));
    int*   indptr  = (int*)  (ws + take((size_t)(N + 1) * 4));
    int*   pos     = (int*)  (ws + take((size_t)E * 4));
    int*   csr_src = (int*)  (ws + take((size_t)E * 4));
    int*   bsum    = (int*)  (ws + take(((size_t)N / 256 + 2) * 4));
    int*   bbase   = (int*)  (ws + take(((size_t)N / 256 + 2) * 4));
    unsigned short* wbf = (unsigned short*)(ws + take(32768 * 2));
    float*          wf  = (float*)         (ws + take(8192 * 4));
    unsigned short* hbuf = (unsigned short*)(ws + take((size_t)N * DIN * 2));
    unsigned short* abuf = (unsigned short*)(ws + take((size_t)N * DIN * 2));
    (void)ws_size; (void)n_in; (void)out_size;

    const int TB = 256;
    dim3 blk(TB);
    const int NB = (N + 255) / 256;

    detect_kernel<<<dim3(1), blk, 0, stream>>>(xu, ei, flags);
    init_cnt_kernel<<<dim3((N + TB - 1) / TB), blk, 0, stream>>>(cnt, N);
    pos_kernel<<<dim3((E + 1023) / 1024), blk, 0, stream>>>(ei, cnt, pos, E, N, flags);
    bsum_kernel<<<dim3(NB), blk, 0, stream>>>(cnt, bsum, N);
    bscan_kernel<<<dim3(1), blk, 0, stream>>>(bsum, bbase, indptr, NB, N);
    emit_kernel<<<dim3(NB), blk, 0, stream>>>(cnt, bbase, indptr, dinv, N);
    scatter_kernel<<<dim3((E + 1023) / 1024), blk, 0, stream>>>(ei, indptr, pos, csr_src, E, N, flags);

    // weight conversion: W1/W2/W3 -> bf16 arena TRANSPOSED; rest -> f32 arena
    WCvt w;
    int bfoff = 0, foff = 0;
    int offs[14];
    const int wcols[14] = {HID1, 0, HID2, 0, HID2, 0, 0, 0, 0, 0, 0, 0, 0, 0};
    for (int a = 0; a < 14; ++a) {
        int idx = a + 2;
        w.p[a] = d_in[idx];
        w.sz[a] = in_sizes[idx];
        int tobf = (idx == 2 || idx == 4 || idx == 6) ? 1 : 0;
        w.tobf[a] = tobf;
        w.cols[a] = tobf ? wcols[a] : 1;
        if (tobf) { w.off[a] = bfoff; bfoff += in_sizes[idx]; }
        else      { w.off[a] = foff;  foff  += in_sizes[idx]; }
        offs[a] = w.off[a];
    }
    wcvt_kernel<<<dim3(64), blk, 0, stream>>>(w, wbf, wf, flags);
    // x -> bf16 into abuf (only if x is f32); abuf is free until agg1 writes it
    xcvt_kernel<<<dim3(512), blk, 0, stream>>>(xf, abuf, N * DIN, flags);

    unsigned short* W1t = wbf + offs[0];   // [128][128] transposed
    unsigned short* W2t = wbf + offs[2];   // [64][128] transposed
    unsigned short* W3t = wbf + offs[4];   // [64][64] transposed
    float* b1f  = wf + offs[1];
    float* b2f  = wf + offs[3];
    float* b3f  = wf + offs[5];
    float* g1f  = wf + offs[6];
    float* be1f = wf + offs[7];
    float* g2f  = wf + offs[8];
    float* be2f = wf + offs[9];
    float* Wp1f = wf + offs[10];
    float* bp1f = wf + offs[11];
    float* Wp2f = wf + offs[12];
    float* bp2f = wf + offs[13];

    const int MMG = (N + 63) / 64;

    // layer 1
    mm_mfma_kernel<DIN, HID1><<<dim3(MMG), blk, 0, stream>>>(xu, abuf, W1t, hbuf, N, flags, 1);
    agg_kernel<HID1, true, false><<<dim3((N + 3) / 4), blk, 0, stream>>>(
        hbuf, indptr, csr_src, dinv, b1f, g1f, be1f, abuf, nullptr, N, flags);

    // layer 2
    mm_mfma_kernel<HID1, HID2><<<dim3(MMG), blk, 0, stream>>>(abuf, nullptr, W2t, hbuf, N, flags, 0);
    agg_kernel<HID2, true, false><<<dim3((N + 3) / 4), blk, 0, stream>>>(
        hbuf, indptr, csr_src, dinv, b2f, g2f, be2f, abuf, nullptr, N, flags);

    // layer 3 -> emb
    mm_mfma_kernel<HID2, HID2><<<dim3(MMG), blk, 0, stream>>>(abuf, nullptr, W3t, hbuf, N, flags, 0);
    agg_kernel<HID2, false, true><<<dim3((N + 3) / 4), blk, 0, stream>>>(
        hbuf, indptr, csr_src, dinv, b3f, nullptr, nullptr, abuf, d_out, N, flags);

    // head
    head_kernel<<<dim3((N + 63) / 64), blk, 0, stream>>>(
        abuf, Wp1f, bp1f, Wp2f, bp2f, d_out, N, flags);
}